// Round 10
// baseline (5657.584 us; speedup 1.0000x reference)
//
#include <hip/hip_runtime.h>
#include <hip/hip_cooperative_groups.h>
#include <stdint.h>

// FFJORD block: B=2048, D=512, H=1024, 9 RK38 steps x 4 stages, 2 Hutchinson probes.
// f32 in/out. bf16 MFMA GEMMs, f32 accumulate, fp32 RK state.
// PRNG: JAX threefry partitionable (verified R7).
// R10: single persistent cooperative kernel (grid.sync between phases) replaces
// 88 launches; all 36 stages' e-matrices pregenerated (151 MB in ws); k_f3
// retiled 64x32 -> 512 tiles. Multi-launch fallback kept if coop launch fails.

#define B_N 2048
#define D_N 512
#define H_N 1024
#define BD (B_N * D_N)

namespace cg = cooperative_groups;

typedef unsigned short u16;
typedef __attribute__((ext_vector_type(8))) short s16x8;   // 8 x bf16
typedef __attribute__((ext_vector_type(4))) float f32x4;   // MFMA accumulator

typedef __attribute__((address_space(1))) const uint32_t ga_u32;
typedef __attribute__((address_space(3))) uint32_t ls_u32;

#if __has_builtin(__builtin_amdgcn_alignbit)
#define ROTL32(x, r) __builtin_amdgcn_alignbit((x), (x), 32 - (r))
#else
#define ROTL32(x, r) (((x) << (r)) | ((x) >> (32 - (r))))
#endif

__device__ __forceinline__ u16 f2bf(float f) {
  union { float f; uint32_t u; } c; c.f = f;
  uint32_t r = c.u + 0x7FFFu + ((c.u >> 16) & 1u);  // RTNE
  return (u16)(r >> 16);
}

struct U2 { uint32_t x, y; };

// Threefry-2x32, 20 rounds — KAT-verified.
__device__ __forceinline__ U2 tf2x32(uint32_t k0, uint32_t k1, uint32_t x0, uint32_t x1) {
  uint32_t k2 = k0 ^ k1 ^ 0x1BD11BDAu;
#define RND(r) { x0 += x1; x1 = ROTL32(x1, r); x1 ^= x0; }
  x0 += k0; x1 += k1;
  RND(13) RND(15) RND(26) RND(6)
  x0 += k1; x1 += k2 + 1u;
  RND(17) RND(29) RND(16) RND(24)
  x0 += k2; x1 += k0 + 2u;
  RND(13) RND(15) RND(26) RND(6)
  x0 += k0; x1 += k1 + 3u;
  RND(17) RND(29) RND(16) RND(24)
  x0 += k1; x1 += k2 + 4u;
  RND(13) RND(15) RND(26) RND(6)
  x0 += k2; x1 += k0 + 5u;
#undef RND
  U2 r; r.x = x0; r.y = x1; return r;
}

// Partitionable key schedule (verified R7).
__device__ __forceinline__ void keysched_body(uint32_t* ekeys) {
  uint32_t kx = 0u, ky = 1234u;
  for (int s = 0; s < 9; ++s) {
    for (int st = 0; st < 4; ++st) {
      U2 kst = tf2x32(kx, ky, 0u, (uint32_t)(st + 1));
      for (int pr = 0; pr < 2; ++pr) {
        U2 fo = tf2x32(kst.x, kst.y, 0u, (uint32_t)pr);
        U2 k2 = tf2x32(fo.x, fo.y, 0u, 1u);
        ekeys[(s * 4 + st) * 4 + pr * 2 + 0] = k2.x;
        ekeys[(s * 4 + st) * 4 + pr * 2 + 1] = k2.y;
      }
    }
    U2 c = tf2x32(kx, ky, 0u, 0u);
    kx = c.x; ky = c.y;
  }
}

// One e-gen item: 32 bf16 +-1 values for (stage=t2>>16, probe, idx).
// e_p = lsb(x^y) of tf(k2, (0,p)) (partitionable random_bits, xor combine).
__device__ __forceinline__ void egen_item(int t2, u16* __restrict__ ebf,
                                          const uint32_t* __restrict__ keys) {
  int stage = t2 >> 16, rem = t2 & 65535;
  int probe = rem >> 15, idx = rem & 32767;
  uint32_t p0 = (uint32_t)idx * 32;
  uint32_t k0 = keys[stage * 4 + probe * 2], k1 = keys[stage * 4 + probe * 2 + 1];
  uint4* dst = (uint4*)(ebf + (size_t)stage * (2 * (size_t)BD) + (size_t)probe * BD + (size_t)idx * 32);
#pragma unroll
  for (int g = 0; g < 4; ++g) {
    uint32_t pr[4];
#pragma unroll
    for (int h = 0; h < 4; ++h) {
      uint32_t c0 = p0 + g * 8 + h * 2;
      U2 r0 = tf2x32(k0, k1, 0u, c0);
      U2 r1 = tf2x32(k0, k1, 0u, c0 + 1u);
      pr[h] = (((r0.x ^ r0.y) & 1u) ? 0x3F80u : 0xBF80u) |
              (((r1.x ^ r1.y) & 1u) ? 0x3F800000u : 0xBF800000u);
    }
    uint4 v; v.x = pr[0]; v.y = pr[1]; v.z = pr[2]; v.w = pr[3];
    dst[g] = v;
  }
}

// Fused 5-product GEMM tile (64x64, K=512), double-buffered DMA (verified R9).
__device__ __forceinline__ void f1_tile(u16* S, int tile,
    const u16* __restrict__ zin, const u16* __restrict__ e0g, const u16* __restrict__ e1g,
    const u16* __restrict__ W1T, const u16* __restrict__ W2b,
    const float* __restrict__ b1v, const float* __restrict__ tw1v, float tstage,
    u16* __restrict__ hbuf, float* __restrict__ div0, float* __restrict__ div1) {
  const int tid = threadIdx.x, wave = tid >> 6, lane = tid & 63;
  const int bm = tile >> 4, bh = tile & 15;
  const int row0 = bm * 64, col0 = bh * 64;
  const int wm = wave >> 1, wn = wave & 1, r16 = lane & 15, q = lane >> 4;
  const int srow = lane >> 2, scol = (lane & 3) * 8;

  f32x4 az[2][2], au0[2][2], au1[2][2], av0[2][2], av1[2][2];
#pragma unroll
  for (int i = 0; i < 2; ++i)
#pragma unroll
    for (int j = 0; j < 2; ++j) {
      az[i][j] = (f32x4){0,0,0,0}; au0[i][j] = (f32x4){0,0,0,0}; au1[i][j] = (f32x4){0,0,0,0};
      av0[i][j] = (f32x4){0,0,0,0}; av1[i][j] = (f32x4){0,0,0,0};
    }

  const size_t arow = (size_t)(row0 + wave * 16 + srow) * 512 + scol;
  const size_t brow = (size_t)(col0 + wave * 16 + srow) * 512 + scol;
  auto stage = [&](int kt, int buf) {
    u16* b = S + buf * 10240;
    __builtin_amdgcn_global_load_lds((ga_u32*)(zin + arow + kt), (ls_u32*)(b + 0    + wave * 512), 16, 0, 0);
    __builtin_amdgcn_global_load_lds((ga_u32*)(e0g + arow + kt), (ls_u32*)(b + 2048 + wave * 512), 16, 0, 0);
    __builtin_amdgcn_global_load_lds((ga_u32*)(e1g + arow + kt), (ls_u32*)(b + 4096 + wave * 512), 16, 0, 0);
    __builtin_amdgcn_global_load_lds((ga_u32*)(W1T + brow + kt), (ls_u32*)(b + 6144 + wave * 512), 16, 0, 0);
    __builtin_amdgcn_global_load_lds((ga_u32*)(W2b + brow + kt), (ls_u32*)(b + 8192 + wave * 512), 16, 0, 0);
  };
  stage(0, 0);
  for (int it = 0; it < 16; ++it) {
    const int buf = it & 1;
    __syncthreads();
    if (it + 1 < 16) stage((it + 1) * 32, buf ^ 1);
    const u16* b = S + buf * 10240;
    s16x8 zf[2], e0f[2], e1f[2], w1f[2], w2f[2];
#pragma unroll
    for (int i = 0; i < 2; ++i) {
      const int ao = (wm * 32 + i * 16 + r16) * 32 + q * 8;
      zf[i]  = *(const s16x8*)(b + 0    + ao);
      e0f[i] = *(const s16x8*)(b + 2048 + ao);
      e1f[i] = *(const s16x8*)(b + 4096 + ao);
    }
#pragma unroll
    for (int j = 0; j < 2; ++j) {
      const int bo = (wn * 32 + j * 16 + r16) * 32 + q * 8;
      w1f[j] = *(const s16x8*)(b + 6144 + bo);
      w2f[j] = *(const s16x8*)(b + 8192 + bo);
    }
#pragma unroll
    for (int i = 0; i < 2; ++i)
#pragma unroll
      for (int j = 0; j < 2; ++j) {
        az[i][j]  = __builtin_amdgcn_mfma_f32_16x16x32_bf16(zf[i],  w1f[j], az[i][j],  0, 0, 0);
        au0[i][j] = __builtin_amdgcn_mfma_f32_16x16x32_bf16(e0f[i], w1f[j], au0[i][j], 0, 0, 0);
        au1[i][j] = __builtin_amdgcn_mfma_f32_16x16x32_bf16(e1f[i], w1f[j], au1[i][j], 0, 0, 0);
        av0[i][j] = __builtin_amdgcn_mfma_f32_16x16x32_bf16(e0f[i], w2f[j], av0[i][j], 0, 0, 0);
        av1[i][j] = __builtin_amdgcn_mfma_f32_16x16x32_bf16(e1f[i], w2f[j], av1[i][j], 0, 0, 0);
      }
  }

  float d0s[2][4], d1s[2][4];
#pragma unroll
  for (int i = 0; i < 2; ++i)
#pragma unroll
    for (int r = 0; r < 4; ++r) { d0s[i][r] = 0.f; d1s[i][r] = 0.f; }

#pragma unroll
  for (int j = 0; j < 2; ++j) {
    const int gcol = col0 + wn * 32 + j * 16 + r16;
    const float colb = b1v[gcol] + tstage * tw1v[gcol];
#pragma unroll
    for (int i = 0; i < 2; ++i) {
      const int rbase = row0 + wm * 32 + i * 16 + q * 4;   // C/D: row=quad*4+reg
#pragma unroll
      for (int r = 0; r < 4; ++r) {
        float hv = tanhf(az[i][j][r] + colb);
        hbuf[(size_t)(rbase + r) * H_N + gcol] = f2bf(hv);
        float s = 1.f - hv * hv;
        d0s[i][r] += s * au0[i][j][r] * av0[i][j][r];
        d1s[i][r] += s * au1[i][j][r] * av1[i][j][r];
      }
    }
  }
#pragma unroll
  for (int i = 0; i < 2; ++i)
#pragma unroll
    for (int r = 0; r < 4; ++r) {
      float a = d0s[i][r], bb = d1s[i][r];
#pragma unroll
      for (int m = 1; m < 16; m <<= 1) { a += __shfl_xor(a, m); bb += __shfl_xor(bb, m); }
      if (r16 == 0) {
        int grow = row0 + wm * 32 + i * 16 + q * 4 + r;
        atomicAdd(&div0[grow], a);
        atomicAdd(&div1[grow], bb);
      }
    }
}

// GEMM3 tile (64x32, K=1024): f = h@W2 + b2 with RK38 epilogue + fused divapply.
// 4 waves of 16x32 wave-tiles; double-buffered DMA. 512 tiles fill the grid.
__device__ __forceinline__ void f3_tile(u16* S, int tile,
    const u16* __restrict__ hbuf, const u16* __restrict__ W2T, const float* __restrict__ b2v,
    float* __restrict__ z, float* __restrict__ ACC, float* __restrict__ T,
    u16* __restrict__ zin, float dt, int st,
    float* __restrict__ lp, float* __restrict__ div0, float* __restrict__ div1, float wdt) {
  const int tid = threadIdx.x, wave = tid >> 6, lane = tid & 63;
  const int bm = tile >> 4, bn = tile & 15;
  const int row0 = bm * 64, col0 = bn * 32;
  const int r16 = lane & 15, q = lane >> 4;
  const int srow = lane >> 2, scol = (lane & 3) * 8;

  if (bn == 0 && tid < 64) {
    int b = row0 + tid;
    float c = 0.5f * (div0[b] + div1[b]);
    c = fminf(fmaxf(c, -100.f), 100.f);
    lp[b] -= wdt * c;
    div0[b] = 0.f; div1[b] = 0.f;
  }

  f32x4 acc[2];
  acc[0] = (f32x4){0,0,0,0}; acc[1] = (f32x4){0,0,0,0};

  const size_t arow = (size_t)(row0 + wave * 16 + srow) * 1024 + scol;
  const size_t brow = (size_t)(col0 + (wave & 1) * 16 + srow) * 1024 + scol;
  auto stage = [&](int kt, int buf) {
    u16* b = S + buf * 10240;
    __builtin_amdgcn_global_load_lds((ga_u32*)(hbuf + arow + kt), (ls_u32*)(b + wave * 512), 16, 0, 0);
    if (wave < 2)
      __builtin_amdgcn_global_load_lds((ga_u32*)(W2T + brow + kt), (ls_u32*)(b + 2048 + wave * 512), 16, 0, 0);
  };
  stage(0, 0);
  for (int it = 0; it < 32; ++it) {
    const int buf = it & 1;
    __syncthreads();
    if (it + 1 < 32) stage((it + 1) * 32, buf ^ 1);
    const u16* b = S + buf * 10240;
    s16x8 af  = *(const s16x8*)(b + (wave * 16 + r16) * 32 + q * 8);
    s16x8 bf0 = *(const s16x8*)(b + 2048 + r16 * 32 + q * 8);
    s16x8 bf1 = *(const s16x8*)(b + 2048 + (16 + r16) * 32 + q * 8);
    acc[0] = __builtin_amdgcn_mfma_f32_16x16x32_bf16(af, bf0, acc[0], 0, 0, 0);
    acc[1] = __builtin_amdgcn_mfma_f32_16x16x32_bf16(af, bf1, acc[1], 0, 0, 0);
  }

#pragma unroll
  for (int j = 0; j < 2; ++j) {
    const int gcol = col0 + j * 16 + r16;
    const float cb = b2v[gcol];
    const int rbase = row0 + wave * 16 + q * 4;
#pragma unroll
    for (int r = 0; r < 4; ++r) {
      const size_t idx = (size_t)(rbase + r) * D_N + gcol;
      const float f = acc[j][r] + cb;
      if (st == 0) {
        ACC[idx] = dt * 0.125f * f;
        T[idx]   = dt * f;
        zin[idx] = f2bf(z[idx] + dt * f * (1.f / 3.f));
      } else if (st == 1) {
        float t_ = T[idx];
        ACC[idx] += 0.375f * dt * f;
        zin[idx] = f2bf(z[idx] + dt * f - t_ * (1.f / 3.f));
        T[idx]   = t_ - dt * f;
      } else if (st == 2) {
        ACC[idx] += 0.375f * dt * f;
        zin[idx] = f2bf(z[idx] + T[idx] + dt * f);
      } else {
        float zn = z[idx] + ACC[idx] + dt * 0.125f * f;
        z[idx]   = zn;
        zin[idx] = f2bf(zn);
      }
    }
  }
}

// ---------------- persistent cooperative kernel ----------------
__global__ __launch_bounds__(256, 2)
void k_main(const float* __restrict__ x, const float* __restrict__ W1,
            const float* __restrict__ b1v, const float* __restrict__ tw1v,
            const float* __restrict__ W2, const float* __restrict__ b2v,
            float* __restrict__ out, uint32_t* __restrict__ keys, u16* __restrict__ ebf,
            float* __restrict__ z, float* __restrict__ ACC, float* __restrict__ T,
            u16* __restrict__ zin, u16* __restrict__ hbuf,
            u16* __restrict__ W1T, u16* __restrict__ W2b, u16* __restrict__ W2T,
            float* __restrict__ lp, float* __restrict__ div0, float* __restrict__ div1) {
  __shared__ u16 S[2 * 10240];   // 40 KB, reused by all phases
  cg::grid_group grid = cg::this_grid();
  const int gtid = blockIdx.x * 256 + threadIdx.x;
  const int gsz = gridDim.x * 256;

  // phase 0: keys + state init + weight conversion
  if (gtid == 0) keysched_body(keys);
  for (int i = gtid; i < BD; i += gsz) { float v = x[i]; z[i] = v; zin[i] = f2bf(v); }
  for (int i = gtid; i < B_N; i += gsz) { lp[i] = 0.f; div0[i] = 0.f; div1[i] = 0.f; }
  for (int i = gtid; i < D_N * H_N; i += gsz) {
    int c = i / D_N, r = i - c * D_N;
    W1T[i] = f2bf(W1[(size_t)r * H_N + c]);
  }
  for (int i = gtid; i < H_N * D_N; i += gsz) W2b[i] = f2bf(W2[i]);
  for (int i = gtid; i < H_N * D_N; i += gsz) {
    int c = i / H_N, r = i - c * H_N;
    W2T[i] = f2bf(W2[(size_t)r * D_N + c]);
  }
  __threadfence();
  grid.sync();

  // phase 0b: all 36 stages' e matrices
  for (int t2 = gtid; t2 < 36 * 65536; t2 += gsz) egen_item(t2, ebf, keys);
  __threadfence();
  grid.sync();

  // main RK loop
  for (int sg = 0; sg < 36; ++sg) {
    const int s = sg >> 2, st = sg & 3;
    const float t0 = (float)s / 9.0f, t1 = (float)(s + 1) / 9.0f, dt = t1 - t0;
    const float tst = (st == 0) ? t0 : (st == 1) ? (t0 + dt / 3.0f)
                   : (st == 2) ? (t0 + dt * 2.0f / 3.0f) : t1;
    const float wdt = dt * 0.125f * ((st == 1 || st == 2) ? 3.0f : 1.0f);
    const u16* e0g = ebf + (size_t)sg * (2 * (size_t)BD);
    const u16* e1g = e0g + BD;
    for (int tile = blockIdx.x; tile < 512; tile += gridDim.x)
      f1_tile(S, tile, zin, e0g, e1g, W1T, W2b, b1v, tw1v, tst, hbuf, div0, div1);
    __threadfence();
    grid.sync();
    for (int tile = blockIdx.x; tile < 512; tile += gridDim.x)
      f3_tile(S, tile, hbuf, W2T, b2v, z, ACC, T, zin, dt, st, lp, div0, div1, wdt);
    __threadfence();
    grid.sync();
  }

  // output phase: rep + logprob
  const int wave = threadIdx.x >> 6, lane = threadIdx.x & 63;
  for (int rb = blockIdx.x; rb < 512; rb += gridDim.x) {
    int b = rb * 4 + wave;
    const float* zr = z + (size_t)b * D_N;
    float ss = 0.f;
    for (int d = lane; d < D_N; d += 64) {
      float v = zr[d];
      out[(size_t)b * D_N + d] = v;
      ss += v * v;
    }
    for (int off = 32; off; off >>= 1) ss += __shfl_down(ss, off);
    if (lane == 0) out[BD + b] = -0.5f * ss + lp[b];
  }
}

// ---------------- fallback multi-launch kernels ----------------
__global__ void k_keysched(uint32_t* __restrict__ ekeys) {
  if (threadIdx.x == 0 && blockIdx.x == 0) keysched_body(ekeys);
}
__global__ void kegen_g(u16* __restrict__ ebf, const uint32_t* __restrict__ keys) {
  int t = blockIdx.x * 256 + threadIdx.x;
  if (t < 36 * 65536) egen_item(t, ebf, keys);
}
__global__ void k_init(const float* __restrict__ x, float* __restrict__ z, u16* __restrict__ zin,
                       float* __restrict__ lp, float* __restrict__ d0, float* __restrict__ d1) {
  int i = blockIdx.x * 256 + threadIdx.x;
  if (i < BD) { float v = x[i]; z[i] = v; zin[i] = f2bf(v); }
  if (i < B_N) { lp[i] = 0.f; d0[i] = 0.f; d1[i] = 0.f; }
}
__global__ void k_cvtT(const float* __restrict__ src, u16* __restrict__ dst, int R, int C) {
  int i = blockIdx.x * 256 + threadIdx.x;
  if (i >= R * C) return;
  int c = i / R, r = i - c * R;
  dst[i] = f2bf(src[(size_t)r * C + c]);
}
__global__ void k_cvt(const float* __restrict__ src, u16* __restrict__ dst, int n) {
  int i = blockIdx.x * 256 + threadIdx.x;
  if (i < n) dst[i] = f2bf(src[i]);
}
__global__ void k_sentinel(float* __restrict__ out, int n) {
  int i = blockIdx.x * 256 + threadIdx.x;
  if (i < n) out[i] = 12345.0f;
}
__global__ __launch_bounds__(256) void kf1_g(
    const u16* zin, const u16* e0g, const u16* e1g, const u16* W1T, const u16* W2b,
    const float* b1v, const float* tw1v, float tstage,
    u16* hbuf, float* div0, float* div1) {
  __shared__ u16 S[2 * 10240];
  f1_tile(S, blockIdx.x, zin, e0g, e1g, W1T, W2b, b1v, tw1v, tstage, hbuf, div0, div1);
}
__global__ __launch_bounds__(256) void kf3_g(
    const u16* hbuf, const u16* W2T, const float* b2v,
    float* z, float* ACC, float* T, u16* zin, float dt, int st,
    float* lp, float* div0, float* div1, float wdt) {
  __shared__ u16 S[2 * 10240];
  f3_tile(S, blockIdx.x, hbuf, W2T, b2v, z, ACC, T, zin, dt, st, lp, div0, div1, wdt);
}
__global__ void k_out(const float* __restrict__ z, const float* __restrict__ lp,
                      float* __restrict__ out) {
  int b = blockIdx.x, t = threadIdx.x;
  const float* zr = z + (size_t)b * D_N;
  float ss = 0.f;
  for (int d = t; d < D_N; d += 256) {
    float v = zr[d];
    out[(size_t)b * D_N + d] = v;
    ss += v * v;
  }
  for (int off = 32; off > 0; off >>= 1) ss += __shfl_down(ss, off);
  __shared__ float red[4];
  if ((t & 63) == 0) red[t >> 6] = ss;
  __syncthreads();
  if (t == 0) out[(size_t)BD + b] = -0.5f * (red[0] + red[1] + red[2] + red[3]) + lp[b];
}

extern "C" void kernel_launch(void* const* d_in, const int* in_sizes, int n_in,
                              void* d_out, int out_size, void* d_ws, size_t ws_size,
                              hipStream_t stream) {
  const float* x   = (const float*)d_in[0];
  const float* W1  = (const float*)d_in[1];
  const float* b1  = (const float*)d_in[2];
  const float* tw1 = (const float*)d_in[3];
  const float* W2  = (const float*)d_in[4];
  const float* b2  = (const float*)d_in[5];
  float* outp = (float*)d_out;

  // ---- workspace carve: ~173 MB (ws = 256 MiB per harness poison fills) ----
  const size_t NEEDED = (size_t)180 << 20;
  if (ws_size < NEEDED) {
    k_sentinel<<<(BD + B_N + 255) / 256, 256, 0, stream>>>(outp, BD + B_N);
    return;
  }
  char* w = (char*)d_ws;
  auto carve = [&](size_t bytes) { char* p = w; w += (bytes + 255) & ~(size_t)255; return p; };
  uint32_t* keys = (uint32_t*)carve(144 * sizeof(uint32_t));
  u16* ebf   = (u16*)carve((size_t)36 * 2 * BD * 2);              // 151 MB: all stages' e
  float* z   = (float*)carve((size_t)BD * 4);
  float* ACC = (float*)carve((size_t)BD * 4);
  float* T   = (float*)carve((size_t)BD * 4);
  u16* zin   = (u16*)carve((size_t)BD * 2);
  u16* hbuf  = (u16*)carve((size_t)B_N * H_N * 2);
  u16* W1T   = (u16*)carve((size_t)H_N * D_N * 2);
  u16* W2b   = (u16*)carve((size_t)H_N * D_N * 2);
  u16* W2T   = (u16*)carve((size_t)D_N * H_N * 2);
  float* lp   = (float*)carve((size_t)B_N * 4);
  float* div0 = (float*)carve((size_t)B_N * 4);
  float* div1 = (float*)carve((size_t)B_N * 4);

  // ---- try the persistent cooperative kernel ----
  int maxb = 0;
  hipError_t orc = hipOccupancyMaxActiveBlocksPerMultiprocessor(&maxb, (const void*)k_main, 256, 0);
  if (orc == hipSuccess && maxb >= 1) {
    int nb = maxb * 256;           // 256 CUs on MI355X
    if (nb > 512) nb = 512;
    void* params[] = { (void*)&x, (void*)&W1, (void*)&b1, (void*)&tw1, (void*)&W2, (void*)&b2,
                       (void*)&outp, (void*)&keys, (void*)&ebf, (void*)&z, (void*)&ACC, (void*)&T,
                       (void*)&zin, (void*)&hbuf, (void*)&W1T, (void*)&W2b, (void*)&W2T,
                       (void*)&lp, (void*)&div0, (void*)&div1 };
    hipError_t rc = hipLaunchCooperativeKernel((const void*)k_main, dim3(nb), dim3(256),
                                               params, 0, stream);
    if (rc == hipSuccess) return;
    (void)hipGetLastError();       // clear error, fall through
  }

  // ---- fallback: R9-style multi-launch path ----
  k_keysched<<<1, 1, 0, stream>>>(keys);
  k_init<<<BD / 256, 256, 0, stream>>>(x, z, zin, lp, div0, div1);
  k_cvtT<<<(D_N * H_N) / 256, 256, 0, stream>>>(W1, W1T, D_N, H_N);
  k_cvt <<<(H_N * D_N) / 256, 256, 0, stream>>>(W2, W2b, H_N * D_N);
  k_cvtT<<<(H_N * D_N) / 256, 256, 0, stream>>>(W2, W2T, H_N, D_N);
  kegen_g<<<(36 * 65536) / 256, 256, 0, stream>>>(ebf, keys);

  for (int s = 0; s < 9; ++s) {
    float t0 = (float)s / 9.0f;
    float t1 = (float)(s + 1) / 9.0f;
    float dt = t1 - t0;
    float tst[4] = { t0, t0 + dt / 3.0f, t0 + dt * 2.0f / 3.0f, t1 };
    float wts[4] = { 1.f, 3.f, 3.f, 1.f };
    for (int st = 0; st < 4; ++st) {
      const int sg = s * 4 + st;
      const u16* e0g = ebf + (size_t)sg * (2 * (size_t)BD);
      const u16* e1g = e0g + BD;
      kf1_g<<<512, 256, 0, stream>>>(zin, e0g, e1g, W1T, W2b, b1, tw1, tst[st], hbuf, div0, div1);
      kf3_g<<<512, 256, 0, stream>>>(hbuf, W2T, b2, z, ACC, T, zin, dt, st,
                                     lp, div0, div1, dt * 0.125f * wts[st]);
    }
  }
  k_out<<<B_N, 256, 0, stream>>>(z, lp, outp);
}

// Round 11
// 1619.032 us; speedup vs baseline: 3.4944x; 3.4944x over previous
//
#include <hip/hip_runtime.h>
#include <stdint.h>

// FFJORD block: B=2048, D=512, H=1024, 9 RK38 steps x 4 stages, 2 Hutchinson probes.
// f32 in/out. bf16 MFMA GEMMs, f32 accumulate, fp32 RK state.
// PRNG: JAX threefry partitionable (verified R7).
// R11: persistent kernel with SLAB-LOCAL atomic barriers (16 blocks/slab) instead
// of grid.sync (R10 showed cg grid.sync ~60us each). All per-stage deps are
// row-slab-local: f1(bm,*) reads zin rows bm; f3(bm,*) reads hbuf rows bm,
// writes zin rows bm. Coop launch only for co-residency; counters memset on host.

#define B_N 2048
#define D_N 512
#define H_N 1024
#define BD (B_N * D_N)

typedef unsigned short u16;
typedef __attribute__((ext_vector_type(8))) short s16x8;   // 8 x bf16
typedef __attribute__((ext_vector_type(4))) float f32x4;   // MFMA accumulator

typedef __attribute__((address_space(1))) const uint32_t ga_u32;
typedef __attribute__((address_space(3))) uint32_t ls_u32;

#if __has_builtin(__builtin_amdgcn_alignbit)
#define ROTL32(x, r) __builtin_amdgcn_alignbit((x), (x), 32 - (r))
#else
#define ROTL32(x, r) (((x) << (r)) | ((x) >> (32 - (r))))
#endif

__device__ __forceinline__ u16 f2bf(float f) {
  union { float f; uint32_t u; } c; c.f = f;
  uint32_t r = c.u + 0x7FFFu + ((c.u >> 16) & 1u);  // RTNE
  return (u16)(r >> 16);
}

struct U2 { uint32_t x, y; };

// Threefry-2x32, 20 rounds — KAT-verified.
__device__ __forceinline__ U2 tf2x32(uint32_t k0, uint32_t k1, uint32_t x0, uint32_t x1) {
  uint32_t k2 = k0 ^ k1 ^ 0x1BD11BDAu;
#define RND(r) { x0 += x1; x1 = ROTL32(x1, r); x1 ^= x0; }
  x0 += k0; x1 += k1;
  RND(13) RND(15) RND(26) RND(6)
  x0 += k1; x1 += k2 + 1u;
  RND(17) RND(29) RND(16) RND(24)
  x0 += k2; x1 += k0 + 2u;
  RND(13) RND(15) RND(26) RND(6)
  x0 += k0; x1 += k1 + 3u;
  RND(17) RND(29) RND(16) RND(24)
  x0 += k1; x1 += k2 + 4u;
  RND(13) RND(15) RND(26) RND(6)
  x0 += k2; x1 += k0 + 5u;
#undef RND
  U2 r; r.x = x0; r.y = x1; return r;
}

// Partitionable key schedule (verified R7).
__device__ __forceinline__ void keysched_body(uint32_t* ekeys) {
  uint32_t kx = 0u, ky = 1234u;
  for (int s = 0; s < 9; ++s) {
    for (int st = 0; st < 4; ++st) {
      U2 kst = tf2x32(kx, ky, 0u, (uint32_t)(st + 1));
      for (int pr = 0; pr < 2; ++pr) {
        U2 fo = tf2x32(kst.x, kst.y, 0u, (uint32_t)pr);
        U2 k2 = tf2x32(fo.x, fo.y, 0u, 1u);
        ekeys[(s * 4 + st) * 4 + pr * 2 + 0] = k2.x;
        ekeys[(s * 4 + st) * 4 + pr * 2 + 1] = k2.y;
      }
    }
    U2 c = tf2x32(kx, ky, 0u, 0u);
    kx = c.x; ky = c.y;
  }
}

// One e-gen item: 32 bf16 +-1 values for (stage, probe, idx).
__device__ __forceinline__ void egen_item(int t2, u16* __restrict__ ebf,
                                          const uint32_t* __restrict__ keys) {
  int stage = t2 >> 16, rem = t2 & 65535;
  int probe = rem >> 15, idx = rem & 32767;
  uint32_t p0 = (uint32_t)idx * 32;
  uint32_t k0 = keys[stage * 4 + probe * 2], k1 = keys[stage * 4 + probe * 2 + 1];
  uint4* dst = (uint4*)(ebf + (size_t)stage * (2 * (size_t)BD) + (size_t)probe * BD + (size_t)idx * 32);
#pragma unroll
  for (int g = 0; g < 4; ++g) {
    uint32_t pr[4];
#pragma unroll
    for (int h = 0; h < 4; ++h) {
      uint32_t c0 = p0 + g * 8 + h * 2;
      U2 r0 = tf2x32(k0, k1, 0u, c0);
      U2 r1 = tf2x32(k0, k1, 0u, c0 + 1u);
      pr[h] = (((r0.x ^ r0.y) & 1u) ? 0x3F80u : 0xBF80u) |
              (((r1.x ^ r1.y) & 1u) ? 0x3F800000u : 0xBF800000u);
    }
    uint4 v; v.x = pr[0]; v.y = pr[1]; v.z = pr[2]; v.w = pr[3];
    dst[g] = v;
  }
}

// Fused 5-product GEMM tile (64x64, K=512), double-buffered DMA (verified R9).
__device__ __forceinline__ void f1_tile(u16* S, int tile,
    const u16* __restrict__ zin, const u16* __restrict__ e0g, const u16* __restrict__ e1g,
    const u16* __restrict__ W1T, const u16* __restrict__ W2b,
    const float* __restrict__ b1v, const float* __restrict__ tw1v, float tstage,
    u16* __restrict__ hbuf, float* __restrict__ div0, float* __restrict__ div1) {
  const int tid = threadIdx.x, wave = tid >> 6, lane = tid & 63;
  const int bm = tile >> 4, bh = tile & 15;
  const int row0 = bm * 64, col0 = bh * 64;
  const int wm = wave >> 1, wn = wave & 1, r16 = lane & 15, q = lane >> 4;
  const int srow = lane >> 2, scol = (lane & 3) * 8;

  f32x4 az[2][2], au0[2][2], au1[2][2], av0[2][2], av1[2][2];
#pragma unroll
  for (int i = 0; i < 2; ++i)
#pragma unroll
    for (int j = 0; j < 2; ++j) {
      az[i][j] = (f32x4){0,0,0,0}; au0[i][j] = (f32x4){0,0,0,0}; au1[i][j] = (f32x4){0,0,0,0};
      av0[i][j] = (f32x4){0,0,0,0}; av1[i][j] = (f32x4){0,0,0,0};
    }

  const size_t arow = (size_t)(row0 + wave * 16 + srow) * 512 + scol;
  const size_t brow = (size_t)(col0 + wave * 16 + srow) * 512 + scol;
  auto stage = [&](int kt, int buf) {
    u16* b = S + buf * 10240;
    __builtin_amdgcn_global_load_lds((ga_u32*)(zin + arow + kt), (ls_u32*)(b + 0    + wave * 512), 16, 0, 0);
    __builtin_amdgcn_global_load_lds((ga_u32*)(e0g + arow + kt), (ls_u32*)(b + 2048 + wave * 512), 16, 0, 0);
    __builtin_amdgcn_global_load_lds((ga_u32*)(e1g + arow + kt), (ls_u32*)(b + 4096 + wave * 512), 16, 0, 0);
    __builtin_amdgcn_global_load_lds((ga_u32*)(W1T + brow + kt), (ls_u32*)(b + 6144 + wave * 512), 16, 0, 0);
    __builtin_amdgcn_global_load_lds((ga_u32*)(W2b + brow + kt), (ls_u32*)(b + 8192 + wave * 512), 16, 0, 0);
  };
  stage(0, 0);
  for (int it = 0; it < 16; ++it) {
    const int buf = it & 1;
    __syncthreads();
    if (it + 1 < 16) stage((it + 1) * 32, buf ^ 1);
    const u16* b = S + buf * 10240;
    s16x8 zf[2], e0f[2], e1f[2], w1f[2], w2f[2];
#pragma unroll
    for (int i = 0; i < 2; ++i) {
      const int ao = (wm * 32 + i * 16 + r16) * 32 + q * 8;
      zf[i]  = *(const s16x8*)(b + 0    + ao);
      e0f[i] = *(const s16x8*)(b + 2048 + ao);
      e1f[i] = *(const s16x8*)(b + 4096 + ao);
    }
#pragma unroll
    for (int j = 0; j < 2; ++j) {
      const int bo = (wn * 32 + j * 16 + r16) * 32 + q * 8;
      w1f[j] = *(const s16x8*)(b + 6144 + bo);
      w2f[j] = *(const s16x8*)(b + 8192 + bo);
    }
#pragma unroll
    for (int i = 0; i < 2; ++i)
#pragma unroll
      for (int j = 0; j < 2; ++j) {
        az[i][j]  = __builtin_amdgcn_mfma_f32_16x16x32_bf16(zf[i],  w1f[j], az[i][j],  0, 0, 0);
        au0[i][j] = __builtin_amdgcn_mfma_f32_16x16x32_bf16(e0f[i], w1f[j], au0[i][j], 0, 0, 0);
        au1[i][j] = __builtin_amdgcn_mfma_f32_16x16x32_bf16(e1f[i], w1f[j], au1[i][j], 0, 0, 0);
        av0[i][j] = __builtin_amdgcn_mfma_f32_16x16x32_bf16(e0f[i], w2f[j], av0[i][j], 0, 0, 0);
        av1[i][j] = __builtin_amdgcn_mfma_f32_16x16x32_bf16(e1f[i], w2f[j], av1[i][j], 0, 0, 0);
      }
  }

  float d0s[2][4], d1s[2][4];
#pragma unroll
  for (int i = 0; i < 2; ++i)
#pragma unroll
    for (int r = 0; r < 4; ++r) { d0s[i][r] = 0.f; d1s[i][r] = 0.f; }

#pragma unroll
  for (int j = 0; j < 2; ++j) {
    const int gcol = col0 + wn * 32 + j * 16 + r16;
    const float colb = b1v[gcol] + tstage * tw1v[gcol];
#pragma unroll
    for (int i = 0; i < 2; ++i) {
      const int rbase = row0 + wm * 32 + i * 16 + q * 4;   // C/D: row=quad*4+reg
#pragma unroll
      for (int r = 0; r < 4; ++r) {
        float hv = tanhf(az[i][j][r] + colb);
        hbuf[(size_t)(rbase + r) * H_N + gcol] = f2bf(hv);
        float s = 1.f - hv * hv;
        d0s[i][r] += s * au0[i][j][r] * av0[i][j][r];
        d1s[i][r] += s * au1[i][j][r] * av1[i][j][r];
      }
    }
  }
#pragma unroll
  for (int i = 0; i < 2; ++i)
#pragma unroll
    for (int r = 0; r < 4; ++r) {
      float a = d0s[i][r], bb = d1s[i][r];
#pragma unroll
      for (int m = 1; m < 16; m <<= 1) { a += __shfl_xor(a, m); bb += __shfl_xor(bb, m); }
      if (r16 == 0) {
        int grow = row0 + wm * 32 + i * 16 + q * 4 + r;
        atomicAdd(&div0[grow], a);
        atomicAdd(&div1[grow], bb);
      }
    }
}

// GEMM3 tile (64x32, K=1024): f = h@W2 + b2 with RK38 epilogue + fused divapply.
__device__ __forceinline__ void f3_tile(u16* S, int tile,
    const u16* __restrict__ hbuf, const u16* __restrict__ W2T, const float* __restrict__ b2v,
    float* __restrict__ z, float* __restrict__ ACC, float* __restrict__ T,
    u16* __restrict__ zin, float dt, int st,
    float* __restrict__ lp, float* __restrict__ div0, float* __restrict__ div1, float wdt) {
  const int tid = threadIdx.x, wave = tid >> 6, lane = tid & 63;
  const int bm = tile >> 4, bn = tile & 15;
  const int row0 = bm * 64, col0 = bn * 32;
  const int r16 = lane & 15, q = lane >> 4;
  const int srow = lane >> 2, scol = (lane & 3) * 8;

  if (bn == 0 && tid < 64) {
    int b = row0 + tid;
    float c = 0.5f * (div0[b] + div1[b]);
    c = fminf(fmaxf(c, -100.f), 100.f);
    lp[b] -= wdt * c;
    div0[b] = 0.f; div1[b] = 0.f;
  }

  f32x4 acc[2];
  acc[0] = (f32x4){0,0,0,0}; acc[1] = (f32x4){0,0,0,0};

  const size_t arow = (size_t)(row0 + wave * 16 + srow) * 1024 + scol;
  const size_t brow = (size_t)(col0 + (wave & 1) * 16 + srow) * 1024 + scol;
  auto stage = [&](int kt, int buf) {
    u16* b = S + buf * 10240;
    __builtin_amdgcn_global_load_lds((ga_u32*)(hbuf + arow + kt), (ls_u32*)(b + wave * 512), 16, 0, 0);
    if (wave < 2)
      __builtin_amdgcn_global_load_lds((ga_u32*)(W2T + brow + kt), (ls_u32*)(b + 2048 + wave * 512), 16, 0, 0);
  };
  stage(0, 0);
  for (int it = 0; it < 32; ++it) {
    const int buf = it & 1;
    __syncthreads();
    if (it + 1 < 32) stage((it + 1) * 32, buf ^ 1);
    const u16* b = S + buf * 10240;
    s16x8 af  = *(const s16x8*)(b + (wave * 16 + r16) * 32 + q * 8);
    s16x8 bf0 = *(const s16x8*)(b + 2048 + r16 * 32 + q * 8);
    s16x8 bf1 = *(const s16x8*)(b + 2048 + (16 + r16) * 32 + q * 8);
    acc[0] = __builtin_amdgcn_mfma_f32_16x16x32_bf16(af, bf0, acc[0], 0, 0, 0);
    acc[1] = __builtin_amdgcn_mfma_f32_16x16x32_bf16(af, bf1, acc[1], 0, 0, 0);
  }

#pragma unroll
  for (int j = 0; j < 2; ++j) {
    const int gcol = col0 + j * 16 + r16;
    const float cb = b2v[gcol];
    const int rbase = row0 + wave * 16 + q * 4;
#pragma unroll
    for (int r = 0; r < 4; ++r) {
      const size_t idx = (size_t)(rbase + r) * D_N + gcol;
      const float f = acc[j][r] + cb;
      if (st == 0) {
        ACC[idx] = dt * 0.125f * f;
        T[idx]   = dt * f;
        zin[idx] = f2bf(z[idx] + dt * f * (1.f / 3.f));
      } else if (st == 1) {
        float t_ = T[idx];
        ACC[idx] += 0.375f * dt * f;
        zin[idx] = f2bf(z[idx] + dt * f - t_ * (1.f / 3.f));
        T[idx]   = t_ - dt * f;
      } else if (st == 2) {
        ACC[idx] += 0.375f * dt * f;
        zin[idx] = f2bf(z[idx] + T[idx] + dt * f);
      } else {
        float zn = z[idx] + ACC[idx] + dt * 0.125f * f;
        z[idx]   = zn;
        zin[idx] = f2bf(zn);
      }
    }
  }
}

// Atomic arrive/spin barrier (counter pre-zeroed by hipMemsetAsync; monotonic target).
__device__ __forceinline__ void bar_sync(uint32_t* cnt, uint32_t target) {
  __syncthreads();
  __threadfence();   // release: L2 writeback so peers (any XCD) see our stores
  if (threadIdx.x == 0) {
    __hip_atomic_fetch_add(cnt, 1u, __ATOMIC_RELAXED, __HIP_MEMORY_SCOPE_AGENT);
    uint32_t v = __hip_atomic_load(cnt, __ATOMIC_RELAXED, __HIP_MEMORY_SCOPE_AGENT);
    while (v < target) {
      __builtin_amdgcn_s_sleep(2);
      v = __hip_atomic_load(cnt, __ATOMIC_RELAXED, __HIP_MEMORY_SCOPE_AGENT);
    }
  }
  __syncthreads();
  __threadfence();   // acquire: invalidate caches before reading peers' data
}

// ---------------- persistent kernel (coop-launched for co-residency) ----------------
__global__ __launch_bounds__(256, 2)
void k_main(const float* __restrict__ x, const float* __restrict__ W1,
            const float* __restrict__ b1v, const float* __restrict__ tw1v,
            const float* __restrict__ W2, const float* __restrict__ b2v,
            float* __restrict__ out, uint32_t* __restrict__ keys, u16* __restrict__ ebf,
            float* __restrict__ z, float* __restrict__ ACC, float* __restrict__ T,
            u16* __restrict__ zin, u16* __restrict__ hbuf,
            u16* __restrict__ W1T, u16* __restrict__ W2b, u16* __restrict__ W2T,
            float* __restrict__ lp, float* __restrict__ div0, float* __restrict__ div1,
            uint32_t* __restrict__ bar) {
  __shared__ u16 S[2 * 10240];   // 40 KB
  const int gtid = blockIdx.x * 256 + threadIdx.x;
  const int gsz = gridDim.x * 256;
  const int slab = blockIdx.x >> 4;   // 32 slabs x 16 blocks
  const int li   = blockIdx.x & 15;
  uint32_t* scnt = bar + slab * 32;         // 128B-strided slab counters
  uint32_t* gcnt = bar + 32 * 32;           // global counter

  // phase 0: keys + state init + weight conversion (grid-stride)
  if (gtid == 0) keysched_body(keys);
  for (int i = gtid; i < BD; i += gsz) { float v = x[i]; z[i] = v; zin[i] = f2bf(v); }
  for (int i = gtid; i < B_N; i += gsz) { lp[i] = 0.f; div0[i] = 0.f; div1[i] = 0.f; }
  for (int i = gtid; i < D_N * H_N; i += gsz) {
    int c = i / D_N, r = i - c * D_N;
    W1T[i] = f2bf(W1[(size_t)r * H_N + c]);
  }
  for (int i = gtid; i < H_N * D_N; i += gsz) W2b[i] = f2bf(W2[i]);
  for (int i = gtid; i < H_N * D_N; i += gsz) {
    int c = i / H_N, r = i - c * H_N;
    W2T[i] = f2bf(W2[(size_t)r * D_N + c]);
  }
  bar_sync(gcnt, 512);

  // phase 0b: all 36 stages' e matrices
  for (int t2 = gtid; t2 < 36 * 65536; t2 += gsz) egen_item(t2, ebf, keys);
  bar_sync(gcnt, 1024);

  // main RK loop — only slab-local barriers (16 blocks each)
  uint32_t tgt = 16;
  for (int sg = 0; sg < 36; ++sg) {
    const int s = sg >> 2, st = sg & 3;
    const float t0 = (float)s / 9.0f, t1 = (float)(s + 1) / 9.0f, dt = t1 - t0;
    const float tst = (st == 0) ? t0 : (st == 1) ? (t0 + dt / 3.0f)
                   : (st == 2) ? (t0 + dt * 2.0f / 3.0f) : t1;
    const float wdt = dt * 0.125f * ((st == 1 || st == 2) ? 3.0f : 1.0f);
    const u16* e0g = ebf + (size_t)sg * (2 * (size_t)BD);
    const u16* e1g = e0g + BD;
    f1_tile(S, slab * 16 + li, zin, e0g, e1g, W1T, W2b, b1v, tw1v, tst, hbuf, div0, div1);
    bar_sync(scnt, tgt); tgt += 16;
    f3_tile(S, slab * 16 + li, hbuf, W2T, b2v, z, ACC, T, zin, dt, st, lp, div0, div1, wdt);
    bar_sync(scnt, tgt); tgt += 16;
  }

  // output phase (slab-local): 4 rows per block, 1 row per wave
  {
    const int wave = threadIdx.x >> 6, lane = threadIdx.x & 63;
    int b = slab * 64 + li * 4 + wave;
    const float* zr = z + (size_t)b * D_N;
    float ss = 0.f;
    for (int d = lane; d < D_N; d += 64) {
      float v = zr[d];
      out[(size_t)b * D_N + d] = v;
      ss += v * v;
    }
    for (int off = 32; off; off >>= 1) ss += __shfl_down(ss, off);
    if (lane == 0) out[BD + b] = -0.5f * ss + lp[b];
  }
}

// ---------------- fallback multi-launch kernels (R9-equivalent) ----------------
__global__ void k_keysched(uint32_t* __restrict__ ekeys) {
  if (threadIdx.x == 0 && blockIdx.x == 0) keysched_body(ekeys);
}
__global__ void kegen_g(u16* __restrict__ ebf, const uint32_t* __restrict__ keys) {
  int t = blockIdx.x * 256 + threadIdx.x;
  if (t < 36 * 65536) egen_item(t, ebf, keys);
}
__global__ void k_init(const float* __restrict__ x, float* __restrict__ z, u16* __restrict__ zin,
                       float* __restrict__ lp, float* __restrict__ d0, float* __restrict__ d1) {
  int i = blockIdx.x * 256 + threadIdx.x;
  if (i < BD) { float v = x[i]; z[i] = v; zin[i] = f2bf(v); }
  if (i < B_N) { lp[i] = 0.f; d0[i] = 0.f; d1[i] = 0.f; }
}
__global__ void k_cvtT(const float* __restrict__ src, u16* __restrict__ dst, int R, int C) {
  int i = blockIdx.x * 256 + threadIdx.x;
  if (i >= R * C) return;
  int c = i / R, r = i - c * R;
  dst[i] = f2bf(src[(size_t)r * C + c]);
}
__global__ void k_cvt(const float* __restrict__ src, u16* __restrict__ dst, int n) {
  int i = blockIdx.x * 256 + threadIdx.x;
  if (i < n) dst[i] = f2bf(src[i]);
}
__global__ void k_sentinel(float* __restrict__ out, int n) {
  int i = blockIdx.x * 256 + threadIdx.x;
  if (i < n) out[i] = 12345.0f;
}
__global__ __launch_bounds__(256) void kf1_g(
    const u16* zin, const u16* e0g, const u16* e1g, const u16* W1T, const u16* W2b,
    const float* b1v, const float* tw1v, float tstage,
    u16* hbuf, float* div0, float* div1) {
  __shared__ u16 S[2 * 10240];
  f1_tile(S, blockIdx.x, zin, e0g, e1g, W1T, W2b, b1v, tw1v, tstage, hbuf, div0, div1);
}
__global__ __launch_bounds__(256) void kf3_g(
    const u16* hbuf, const u16* W2T, const float* b2v,
    float* z, float* ACC, float* T, u16* zin, float dt, int st,
    float* lp, float* div0, float* div1, float wdt) {
  __shared__ u16 S[2 * 10240];
  f3_tile(S, blockIdx.x, hbuf, W2T, b2v, z, ACC, T, zin, dt, st, lp, div0, div1, wdt);
}
__global__ void k_out(const float* __restrict__ z, const float* __restrict__ lp,
                      float* __restrict__ out) {
  int b = blockIdx.x, t = threadIdx.x;
  const float* zr = z + (size_t)b * D_N;
  float ss = 0.f;
  for (int d = t; d < D_N; d += 256) {
    float v = zr[d];
    out[(size_t)b * D_N + d] = v;
    ss += v * v;
  }
  for (int off = 32; off > 0; off >>= 1) ss += __shfl_down(ss, off);
  __shared__ float red[4];
  if ((t & 63) == 0) red[t >> 6] = ss;
  __syncthreads();
  if (t == 0) out[(size_t)BD + b] = -0.5f * (red[0] + red[1] + red[2] + red[3]) + lp[b];
}

extern "C" void kernel_launch(void* const* d_in, const int* in_sizes, int n_in,
                              void* d_out, int out_size, void* d_ws, size_t ws_size,
                              hipStream_t stream) {
  const float* x   = (const float*)d_in[0];
  const float* W1  = (const float*)d_in[1];
  const float* b1  = (const float*)d_in[2];
  const float* tw1 = (const float*)d_in[3];
  const float* W2  = (const float*)d_in[4];
  const float* b2  = (const float*)d_in[5];
  float* outp = (float*)d_out;

  const size_t NEEDED = (size_t)180 << 20;
  if (ws_size < NEEDED) {
    k_sentinel<<<(BD + B_N + 255) / 256, 256, 0, stream>>>(outp, BD + B_N);
    return;
  }
  char* w = (char*)d_ws;
  auto carve = [&](size_t bytes) { char* p = w; w += (bytes + 255) & ~(size_t)255; return p; };
  uint32_t* bar  = (uint32_t*)carve(33 * 32 * sizeof(uint32_t));  // 128B-strided counters
  uint32_t* keys = (uint32_t*)carve(144 * sizeof(uint32_t));
  u16* ebf   = (u16*)carve((size_t)36 * 2 * BD * 2);              // 151 MB: all stages' e
  float* z   = (float*)carve((size_t)BD * 4);
  float* ACC = (float*)carve((size_t)BD * 4);
  float* T   = (float*)carve((size_t)BD * 4);
  u16* zin   = (u16*)carve((size_t)BD * 2);
  u16* hbuf  = (u16*)carve((size_t)B_N * H_N * 2);
  u16* W1T   = (u16*)carve((size_t)H_N * D_N * 2);
  u16* W2b   = (u16*)carve((size_t)H_N * D_N * 2);
  u16* W2T   = (u16*)carve((size_t)D_N * H_N * 2);
  float* lp   = (float*)carve((size_t)B_N * 4);
  float* div0 = (float*)carve((size_t)B_N * 4);
  float* div1 = (float*)carve((size_t)B_N * 4);

  // ---- try the persistent kernel (coop launch guarantees co-residency) ----
  int maxb = 0;
  hipError_t orc = hipOccupancyMaxActiveBlocksPerMultiprocessor(&maxb, (const void*)k_main, 256, 0);
  if (orc == hipSuccess && maxb >= 2) {
    hipMemsetAsync(bar, 0, 33 * 32 * sizeof(uint32_t), stream);   // barrier counters := 0
    void* params[] = { (void*)&x, (void*)&W1, (void*)&b1, (void*)&tw1, (void*)&W2, (void*)&b2,
                       (void*)&outp, (void*)&keys, (void*)&ebf, (void*)&z, (void*)&ACC, (void*)&T,
                       (void*)&zin, (void*)&hbuf, (void*)&W1T, (void*)&W2b, (void*)&W2T,
                       (void*)&lp, (void*)&div0, (void*)&div1, (void*)&bar };
    hipError_t rc = hipLaunchCooperativeKernel((const void*)k_main, dim3(512), dim3(256),
                                               params, 0, stream);
    if (rc == hipSuccess) return;
    (void)hipGetLastError();
  }

  // ---- fallback: multi-launch path ----
  k_keysched<<<1, 1, 0, stream>>>(keys);
  k_init<<<BD / 256, 256, 0, stream>>>(x, z, zin, lp, div0, div1);
  k_cvtT<<<(D_N * H_N) / 256, 256, 0, stream>>>(W1, W1T, D_N, H_N);
  k_cvt <<<(H_N * D_N) / 256, 256, 0, stream>>>(W2, W2b, H_N * D_N);
  k_cvtT<<<(H_N * D_N) / 256, 256, 0, stream>>>(W2, W2T, H_N, D_N);
  kegen_g<<<(36 * 65536) / 256, 256, 0, stream>>>(ebf, keys);

  for (int s = 0; s < 9; ++s) {
    float t0 = (float)s / 9.0f;
    float t1 = (float)(s + 1) / 9.0f;
    float dt = t1 - t0;
    float tst[4] = { t0, t0 + dt / 3.0f, t0 + dt * 2.0f / 3.0f, t1 };
    float wts[4] = { 1.f, 3.f, 3.f, 1.f };
    for (int st = 0; st < 4; ++st) {
      const int sg = s * 4 + st;
      const u16* e0g = ebf + (size_t)sg * (2 * (size_t)BD);
      const u16* e1g = e0g + BD;
      kf1_g<<<512, 256, 0, stream>>>(zin, e0g, e1g, W1T, W2b, b1, tw1, tst[st], hbuf, div0, div1);
      kf3_g<<<512, 256, 0, stream>>>(hbuf, W2T, b2, z, ACC, T, zin, dt, st,
                                     lp, div0, div1, dt * 0.125f * wts[st]);
    }
  }
  k_out<<<B_N, 256, 0, stream>>>(z, lp, outp);
}

// Round 12
// 1572.507 us; speedup vs baseline: 3.5978x; 1.0296x over previous
//
#include <hip/hip_runtime.h>
#include <stdint.h>

// FFJORD block: B=2048, D=512, H=1024, 9 RK38 steps x 4 stages, 2 Hutchinson probes.
// f32 in/out. bf16 MFMA GEMMs, f32 accumulate, fp32 RK state.
// PRNG: JAX threefry partitionable (verified R7).
// R12: persistent kernel with PIPELINED producer-consumer flags instead of slab
// barriers (R11). Block (slab,li): f1 tile -> flag -> f3 tile consuming 16
// K-chunks in rotated order (own chunk first), polling per-chunk flags just
// before chunked double-buffered DMA. One monotonic per-slab counter per stage
// guards WAR on hbuf/zin. Coop launch for co-residency only; fallback = R9 path.

#define B_N 2048
#define D_N 512
#define H_N 1024
#define BD (B_N * D_N)

typedef unsigned short u16;
typedef __attribute__((ext_vector_type(8))) short s16x8;   // 8 x bf16
typedef __attribute__((ext_vector_type(4))) float f32x4;   // MFMA accumulator

typedef __attribute__((address_space(1))) const uint32_t ga_u32;
typedef __attribute__((address_space(3))) uint32_t ls_u32;

#if __has_builtin(__builtin_amdgcn_alignbit)
#define ROTL32(x, r) __builtin_amdgcn_alignbit((x), (x), 32 - (r))
#else
#define ROTL32(x, r) (((x) << (r)) | ((x) >> (32 - (r))))
#endif

__device__ __forceinline__ u16 f2bf(float f) {
  union { float f; uint32_t u; } c; c.f = f;
  uint32_t r = c.u + 0x7FFFu + ((c.u >> 16) & 1u);  // RTNE
  return (u16)(r >> 16);
}
__device__ __forceinline__ float fast_tanh(float v) {
  float e = __expf(2.0f * fabsf(v));
  float t = 1.0f - 2.0f / (e + 1.0f);
  return copysignf(t, v);
}

struct U2 { uint32_t x, y; };

// Threefry-2x32, 20 rounds — KAT-verified.
__device__ __forceinline__ U2 tf2x32(uint32_t k0, uint32_t k1, uint32_t x0, uint32_t x1) {
  uint32_t k2 = k0 ^ k1 ^ 0x1BD11BDAu;
#define RND(r) { x0 += x1; x1 = ROTL32(x1, r); x1 ^= x0; }
  x0 += k0; x1 += k1;
  RND(13) RND(15) RND(26) RND(6)
  x0 += k1; x1 += k2 + 1u;
  RND(17) RND(29) RND(16) RND(24)
  x0 += k2; x1 += k0 + 2u;
  RND(13) RND(15) RND(26) RND(6)
  x0 += k0; x1 += k1 + 3u;
  RND(17) RND(29) RND(16) RND(24)
  x0 += k1; x1 += k2 + 4u;
  RND(13) RND(15) RND(26) RND(6)
  x0 += k2; x1 += k0 + 5u;
#undef RND
  U2 r; r.x = x0; r.y = x1; return r;
}

// Partitionable key schedule (verified R7).
__device__ __forceinline__ void keysched_body(uint32_t* ekeys) {
  uint32_t kx = 0u, ky = 1234u;
  for (int s = 0; s < 9; ++s) {
    for (int st = 0; st < 4; ++st) {
      U2 kst = tf2x32(kx, ky, 0u, (uint32_t)(st + 1));
      for (int pr = 0; pr < 2; ++pr) {
        U2 fo = tf2x32(kst.x, kst.y, 0u, (uint32_t)pr);
        U2 k2 = tf2x32(fo.x, fo.y, 0u, 1u);
        ekeys[(s * 4 + st) * 4 + pr * 2 + 0] = k2.x;
        ekeys[(s * 4 + st) * 4 + pr * 2 + 1] = k2.y;
      }
    }
    U2 c = tf2x32(kx, ky, 0u, 0u);
    kx = c.x; ky = c.y;
  }
}

// One e-gen item: 32 bf16 +-1 values for (stage, probe, idx).
__device__ __forceinline__ void egen_item(int t2, u16* __restrict__ ebf,
                                          const uint32_t* __restrict__ keys) {
  int stage = t2 >> 16, rem = t2 & 65535;
  int probe = rem >> 15, idx = rem & 32767;
  uint32_t p0 = (uint32_t)idx * 32;
  uint32_t k0 = keys[stage * 4 + probe * 2], k1 = keys[stage * 4 + probe * 2 + 1];
  uint4* dst = (uint4*)(ebf + (size_t)stage * (2 * (size_t)BD) + (size_t)probe * BD + (size_t)idx * 32);
#pragma unroll
  for (int g = 0; g < 4; ++g) {
    uint32_t pr[4];
#pragma unroll
    for (int h = 0; h < 4; ++h) {
      uint32_t c0 = p0 + g * 8 + h * 2;
      U2 r0 = tf2x32(k0, k1, 0u, c0);
      U2 r1 = tf2x32(k0, k1, 0u, c0 + 1u);
      pr[h] = (((r0.x ^ r0.y) & 1u) ? 0x3F80u : 0xBF80u) |
              (((r1.x ^ r1.y) & 1u) ? 0x3F800000u : 0xBF800000u);
    }
    uint4 v; v.x = pr[0]; v.y = pr[1]; v.z = pr[2]; v.w = pr[3];
    dst[g] = v;
  }
}

// Relaxed poll until *p >= tgt, then acquire fence.
__device__ __forceinline__ void wait_ge(uint32_t* p, uint32_t tgt) {
  while (__hip_atomic_load(p, __ATOMIC_RELAXED, __HIP_MEMORY_SCOPE_AGENT) < tgt)
    __builtin_amdgcn_s_sleep(1);
  __threadfence();
}

// Fused 5-product GEMM tile (64x64, K=512), double-buffered DMA (verified R9).
__device__ __forceinline__ void f1_tile(u16* S, int tile,
    const u16* __restrict__ zin, const u16* __restrict__ e0g, const u16* __restrict__ e1g,
    const u16* __restrict__ W1T, const u16* __restrict__ W2b,
    const float* __restrict__ b1v, const float* __restrict__ tw1v, float tstage,
    u16* __restrict__ hbuf, float* __restrict__ div0, float* __restrict__ div1) {
  const int tid = threadIdx.x, wave = tid >> 6, lane = tid & 63;
  const int bm = tile >> 4, bh = tile & 15;
  const int row0 = bm * 64, col0 = bh * 64;
  const int wm = wave >> 1, wn = wave & 1, r16 = lane & 15, q = lane >> 4;
  const int srow = lane >> 2, scol = (lane & 3) * 8;

  f32x4 az[2][2], au0[2][2], au1[2][2], av0[2][2], av1[2][2];
#pragma unroll
  for (int i = 0; i < 2; ++i)
#pragma unroll
    for (int j = 0; j < 2; ++j) {
      az[i][j] = (f32x4){0,0,0,0}; au0[i][j] = (f32x4){0,0,0,0}; au1[i][j] = (f32x4){0,0,0,0};
      av0[i][j] = (f32x4){0,0,0,0}; av1[i][j] = (f32x4){0,0,0,0};
    }

  const size_t arow = (size_t)(row0 + wave * 16 + srow) * 512 + scol;
  const size_t brow = (size_t)(col0 + wave * 16 + srow) * 512 + scol;
  auto stage = [&](int kt, int buf) {
    u16* b = S + buf * 10240;
    __builtin_amdgcn_global_load_lds((ga_u32*)(zin + arow + kt), (ls_u32*)(b + 0    + wave * 512), 16, 0, 0);
    __builtin_amdgcn_global_load_lds((ga_u32*)(e0g + arow + kt), (ls_u32*)(b + 2048 + wave * 512), 16, 0, 0);
    __builtin_amdgcn_global_load_lds((ga_u32*)(e1g + arow + kt), (ls_u32*)(b + 4096 + wave * 512), 16, 0, 0);
    __builtin_amdgcn_global_load_lds((ga_u32*)(W1T + brow + kt), (ls_u32*)(b + 6144 + wave * 512), 16, 0, 0);
    __builtin_amdgcn_global_load_lds((ga_u32*)(W2b + brow + kt), (ls_u32*)(b + 8192 + wave * 512), 16, 0, 0);
  };
  stage(0, 0);
  for (int it = 0; it < 16; ++it) {
    const int buf = it & 1;
    __syncthreads();
    if (it + 1 < 16) stage((it + 1) * 32, buf ^ 1);
    const u16* b = S + buf * 10240;
    s16x8 zf[2], e0f[2], e1f[2], w1f[2], w2f[2];
#pragma unroll
    for (int i = 0; i < 2; ++i) {
      const int ao = (wm * 32 + i * 16 + r16) * 32 + q * 8;
      zf[i]  = *(const s16x8*)(b + 0    + ao);
      e0f[i] = *(const s16x8*)(b + 2048 + ao);
      e1f[i] = *(const s16x8*)(b + 4096 + ao);
    }
#pragma unroll
    for (int j = 0; j < 2; ++j) {
      const int bo = (wn * 32 + j * 16 + r16) * 32 + q * 8;
      w1f[j] = *(const s16x8*)(b + 6144 + bo);
      w2f[j] = *(const s16x8*)(b + 8192 + bo);
    }
#pragma unroll
    for (int i = 0; i < 2; ++i)
#pragma unroll
      for (int j = 0; j < 2; ++j) {
        az[i][j]  = __builtin_amdgcn_mfma_f32_16x16x32_bf16(zf[i],  w1f[j], az[i][j],  0, 0, 0);
        au0[i][j] = __builtin_amdgcn_mfma_f32_16x16x32_bf16(e0f[i], w1f[j], au0[i][j], 0, 0, 0);
        au1[i][j] = __builtin_amdgcn_mfma_f32_16x16x32_bf16(e1f[i], w1f[j], au1[i][j], 0, 0, 0);
        av0[i][j] = __builtin_amdgcn_mfma_f32_16x16x32_bf16(e0f[i], w2f[j], av0[i][j], 0, 0, 0);
        av1[i][j] = __builtin_amdgcn_mfma_f32_16x16x32_bf16(e1f[i], w2f[j], av1[i][j], 0, 0, 0);
      }
  }

  float d0s[2][4], d1s[2][4];
#pragma unroll
  for (int i = 0; i < 2; ++i)
#pragma unroll
    for (int r = 0; r < 4; ++r) { d0s[i][r] = 0.f; d1s[i][r] = 0.f; }

#pragma unroll
  for (int j = 0; j < 2; ++j) {
    const int gcol = col0 + wn * 32 + j * 16 + r16;
    const float colb = b1v[gcol] + tstage * tw1v[gcol];
#pragma unroll
    for (int i = 0; i < 2; ++i) {
      const int rbase = row0 + wm * 32 + i * 16 + q * 4;   // C/D: row=quad*4+reg
#pragma unroll
      for (int r = 0; r < 4; ++r) {
        float hv = fast_tanh(az[i][j][r] + colb);
        hbuf[(size_t)(rbase + r) * H_N + gcol] = f2bf(hv);
        float s = 1.f - hv * hv;
        d0s[i][r] += s * au0[i][j][r] * av0[i][j][r];
        d1s[i][r] += s * au1[i][j][r] * av1[i][j][r];
      }
    }
  }
#pragma unroll
  for (int i = 0; i < 2; ++i)
#pragma unroll
    for (int r = 0; r < 4; ++r) {
      float a = d0s[i][r], bb = d1s[i][r];
#pragma unroll
      for (int m = 1; m < 16; m <<= 1) { a += __shfl_xor(a, m); bb += __shfl_xor(bb, m); }
      if (r16 == 0) {
        int grow = row0 + wm * 32 + i * 16 + q * 4 + r;
        atomicAdd(&div0[grow], a);
        atomicAdd(&div1[grow], bb);
      }
    }
}

// RK38 stage epilogue shared by both f3 variants.
template<typename ACCT>
__device__ __forceinline__ void f3_epilogue(const ACCT& acc, int row0, int col0,
    int wave, int r16, int q, const float* b2v,
    float* z, float* ACC, float* T, u16* zin, float dt, int st) {
#pragma unroll
  for (int j = 0; j < 2; ++j) {
    const int gcol = col0 + j * 16 + r16;
    const float cb = b2v[gcol];
    const int rbase = row0 + wave * 16 + q * 4;
#pragma unroll
    for (int r = 0; r < 4; ++r) {
      const size_t idx = (size_t)(rbase + r) * D_N + gcol;
      const float f = acc[j][r] + cb;
      if (st == 0) {
        ACC[idx] = dt * 0.125f * f;
        T[idx]   = dt * f;
        zin[idx] = f2bf(z[idx] + dt * f * (1.f / 3.f));
      } else if (st == 1) {
        float t_ = T[idx];
        ACC[idx] += 0.375f * dt * f;
        zin[idx] = f2bf(z[idx] + dt * f - t_ * (1.f / 3.f));
        T[idx]   = t_ - dt * f;
      } else if (st == 2) {
        ACC[idx] += 0.375f * dt * f;
        zin[idx] = f2bf(z[idx] + T[idx] + dt * f);
      } else {
        float zn = z[idx] + ACC[idx] + dt * 0.125f * f;
        z[idx]   = zn;
        zin[idx] = f2bf(zn);
      }
    }
  }
}

// Chunked f3 (64x32 tile): consumes 16 K-chunks of 64 in rotated order, polling
// per-chunk producer flags; double-buffered chunk DMA; lp/div apply after loop.
__device__ __forceinline__ void f3_chunked(u16* S, int slab, int li, int sg,
    const u16* __restrict__ hbuf, const u16* __restrict__ W2T, const float* __restrict__ b2v,
    float* __restrict__ z, float* __restrict__ ACC, float* __restrict__ T,
    u16* __restrict__ zin, float dt, int st,
    float* __restrict__ lp, float* __restrict__ div0, float* __restrict__ div1, float wdt,
    uint32_t* __restrict__ hflag) {
  const int tid = threadIdx.x, wave = tid >> 6, lane = tid & 63;
  const int row0 = slab * 64, col0 = li * 32;
  const int r16 = lane & 15, q = lane >> 4;
  const int srow = lane >> 2, scol = (lane & 3) * 8;

  f32x4 acc[2];
  acc[0] = (f32x4){0,0,0,0}; acc[1] = (f32x4){0,0,0,0};

  const size_t arow = (size_t)(row0 + wave * 16 + srow) * 1024 + scol;
  // per-buffer layout (u16): A0[2048] A1[2048] B0[1024] B1[1024] = 6144
  auto dma = [&](int bh, int buf) {
    u16* b = S + buf * 6144;
    const int k0 = bh * 64;
    __builtin_amdgcn_global_load_lds((ga_u32*)(hbuf + arow + k0),      (ls_u32*)(b + wave * 512), 16, 0, 0);
    __builtin_amdgcn_global_load_lds((ga_u32*)(hbuf + arow + k0 + 32), (ls_u32*)(b + 2048 + wave * 512), 16, 0, 0);
    if (wave < 2)
      __builtin_amdgcn_global_load_lds((ga_u32*)(W2T + (size_t)(col0 + wave * 16 + srow) * 1024 + k0 + scol),
                                       (ls_u32*)(b + 4096 + wave * 512), 16, 0, 0);
    else
      __builtin_amdgcn_global_load_lds((ga_u32*)(W2T + (size_t)(col0 + (wave - 2) * 16 + srow) * 1024 + k0 + 32 + scol),
                                       (ls_u32*)(b + 5120 + (wave - 2) * 512), 16, 0, 0);
  };
  dma(li, 0);   // own chunk — flag already published by this block
  for (int c = 0; c < 16; ++c) {
    const int buf = c & 1;
    __syncthreads();                       // drains DMA for chunk c
    if (c + 1 < 16) {
      int nbh = (li + c + 1) & 15;
      wait_ge(hflag + (slab * 16 + nbh) * 16, (uint32_t)(sg + 1));
      dma(nbh, buf ^ 1);
    }
    const u16* b = S + buf * 6144;
#pragma unroll
    for (int p = 0; p < 2; ++p) {
      s16x8 af  = *(const s16x8*)(b + p * 2048 + (wave * 16 + r16) * 32 + q * 8);
      s16x8 bf0 = *(const s16x8*)(b + 4096 + p * 1024 + r16 * 32 + q * 8);
      s16x8 bf1 = *(const s16x8*)(b + 4096 + p * 1024 + (16 + r16) * 32 + q * 8);
      acc[0] = __builtin_amdgcn_mfma_f32_16x16x32_bf16(af, bf0, acc[0], 0, 0, 0);
      acc[1] = __builtin_amdgcn_mfma_f32_16x16x32_bf16(af, bf1, acc[1], 0, 0, 0);
    }
  }

  if (li == 0 && tid < 64) {   // all 16 flags consumed => all div atomics done
    int b = row0 + tid;
    float c = 0.5f * (div0[b] + div1[b]);
    c = fminf(fmaxf(c, -100.f), 100.f);
    lp[b] -= wdt * c;
    div0[b] = 0.f; div1[b] = 0.f;
  }
  f3_epilogue(acc, row0, col0, wave, r16, q, b2v, z, ACC, T, zin, dt, st);
}

// Mono f3 tile (R11 form) for the multi-launch fallback path.
__device__ __forceinline__ void f3_tile(u16* S, int tile,
    const u16* __restrict__ hbuf, const u16* __restrict__ W2T, const float* __restrict__ b2v,
    float* __restrict__ z, float* __restrict__ ACC, float* __restrict__ T,
    u16* __restrict__ zin, float dt, int st,
    float* __restrict__ lp, float* __restrict__ div0, float* __restrict__ div1, float wdt) {
  const int tid = threadIdx.x, wave = tid >> 6, lane = tid & 63;
  const int bm = tile >> 4, bn = tile & 15;
  const int row0 = bm * 64, col0 = bn * 32;
  const int r16 = lane & 15, q = lane >> 4;
  const int srow = lane >> 2, scol = (lane & 3) * 8;

  if (bn == 0 && tid < 64) {
    int b = row0 + tid;
    float c = 0.5f * (div0[b] + div1[b]);
    c = fminf(fmaxf(c, -100.f), 100.f);
    lp[b] -= wdt * c;
    div0[b] = 0.f; div1[b] = 0.f;
  }
  f32x4 acc[2];
  acc[0] = (f32x4){0,0,0,0}; acc[1] = (f32x4){0,0,0,0};
  const size_t arow = (size_t)(row0 + wave * 16 + srow) * 1024 + scol;
  const size_t brow = (size_t)(col0 + (wave & 1) * 16 + srow) * 1024 + scol;
  auto stg = [&](int kt, int buf) {
    u16* b = S + buf * 10240;
    __builtin_amdgcn_global_load_lds((ga_u32*)(hbuf + arow + kt), (ls_u32*)(b + wave * 512), 16, 0, 0);
    if (wave < 2)
      __builtin_amdgcn_global_load_lds((ga_u32*)(W2T + brow + kt), (ls_u32*)(b + 2048 + wave * 512), 16, 0, 0);
  };
  stg(0, 0);
  for (int it = 0; it < 32; ++it) {
    const int buf = it & 1;
    __syncthreads();
    if (it + 1 < 32) stg((it + 1) * 32, buf ^ 1);
    const u16* b = S + buf * 10240;
    s16x8 af  = *(const s16x8*)(b + (wave * 16 + r16) * 32 + q * 8);
    s16x8 bf0 = *(const s16x8*)(b + 2048 + r16 * 32 + q * 8);
    s16x8 bf1 = *(const s16x8*)(b + 2048 + (16 + r16) * 32 + q * 8);
    acc[0] = __builtin_amdgcn_mfma_f32_16x16x32_bf16(af, bf0, acc[0], 0, 0, 0);
    acc[1] = __builtin_amdgcn_mfma_f32_16x16x32_bf16(af, bf1, acc[1], 0, 0, 0);
  }
  f3_epilogue(acc, row0, col0, wave, r16, q, b2v, z, ACC, T, zin, dt, st);
}

// Global arrive/spin barrier for the setup phases (R11-verified).
__device__ __forceinline__ void bar_sync(uint32_t* cnt, uint32_t target) {
  __syncthreads();
  __threadfence();
  if (threadIdx.x == 0) {
    __hip_atomic_fetch_add(cnt, 1u, __ATOMIC_RELAXED, __HIP_MEMORY_SCOPE_AGENT);
    while (__hip_atomic_load(cnt, __ATOMIC_RELAXED, __HIP_MEMORY_SCOPE_AGENT) < target)
      __builtin_amdgcn_s_sleep(2);
  }
  __syncthreads();
  __threadfence();
}

// ---------------- persistent kernel (coop-launched for co-residency) ----------------
__global__ __launch_bounds__(256, 2)
void k_main(const float* __restrict__ x, const float* __restrict__ W1,
            const float* __restrict__ b1v, const float* __restrict__ tw1v,
            const float* __restrict__ W2, const float* __restrict__ b2v,
            float* __restrict__ out, uint32_t* __restrict__ keys, u16* __restrict__ ebf,
            float* __restrict__ z, float* __restrict__ ACC, float* __restrict__ T,
            u16* __restrict__ zin, u16* __restrict__ hbuf,
            u16* __restrict__ W1T, u16* __restrict__ W2b, u16* __restrict__ W2T,
            float* __restrict__ lp, float* __restrict__ div0, float* __restrict__ div1,
            uint32_t* __restrict__ bar) {
  __shared__ u16 S[2 * 10240];   // 40 KB
  const int gtid = blockIdx.x * 256 + threadIdx.x;
  const int gsz = gridDim.x * 256;
  const int slab = blockIdx.x >> 4;   // 32 slabs x 16 blocks
  const int li   = blockIdx.x & 15;
  uint32_t* gcnt  = bar;                    // [0]
  uint32_t* zcnt  = bar + 32 + slab * 32;   // 128B-strided per-slab counters
  uint32_t* hflag = bar + 2048;             // 512 flags, 64B stride

  // phase 0: keys + state init + weight conversion (grid-stride)
  if (gtid == 0) keysched_body(keys);
  for (int i = gtid; i < BD; i += gsz) { float v = x[i]; z[i] = v; zin[i] = f2bf(v); }
  for (int i = gtid; i < B_N; i += gsz) { lp[i] = 0.f; div0[i] = 0.f; div1[i] = 0.f; }
  for (int i = gtid; i < D_N * H_N; i += gsz) {
    int c = i / D_N, r = i - c * D_N;
    W1T[i] = f2bf(W1[(size_t)r * H_N + c]);
  }
  for (int i = gtid; i < H_N * D_N; i += gsz) W2b[i] = f2bf(W2[i]);
  for (int i = gtid; i < H_N * D_N; i += gsz) {
    int c = i / H_N, r = i - c * H_N;
    W2T[i] = f2bf(W2[(size_t)r * D_N + c]);
  }
  bar_sync(gcnt, 512);

  // phase 0b: all 36 stages' e matrices
  for (int t2 = gtid; t2 < 36 * 65536; t2 += gsz) egen_item(t2, ebf, keys);
  bar_sync(gcnt, 1024);

  // main RK loop — pipelined dataflow
  for (int sg = 0; sg < 36; ++sg) {
    const int s = sg >> 2, st = sg & 3;
    const float t0 = (float)s / 9.0f, t1 = (float)(s + 1) / 9.0f, dt = t1 - t0;
    const float tst = (st == 0) ? t0 : (st == 1) ? (t0 + dt / 3.0f)
                   : (st == 2) ? (t0 + dt * 2.0f / 3.0f) : t1;
    const float wdt = dt * 0.125f * ((st == 1 || st == 2) ? 3.0f : 1.0f);
    const u16* e0g = ebf + (size_t)sg * (2 * (size_t)BD);
    const u16* e1g = e0g + BD;

    if (sg) wait_ge(zcnt, (uint32_t)(16 * sg));   // WAR: slab's prev-stage f3 done

    f1_tile(S, slab * 16 + li, zin, e0g, e1g, W1T, W2b, b1v, tw1v, tst, hbuf, div0, div1);
    __syncthreads();
    __threadfence();
    if (threadIdx.x == 0)
      __hip_atomic_store(hflag + (slab * 16 + li) * 16, (uint32_t)(sg + 1),
                         __ATOMIC_RELEASE, __HIP_MEMORY_SCOPE_AGENT);

    f3_chunked(S, slab, li, sg, hbuf, W2T, b2v, z, ACC, T, zin, dt, st,
               lp, div0, div1, wdt, hflag);
    __syncthreads();
    __threadfence();
    if (threadIdx.x == 0)
      __hip_atomic_fetch_add(zcnt, 1u, __ATOMIC_RELEASE, __HIP_MEMORY_SCOPE_AGENT);
  }

  // output phase (slab-local)
  wait_ge(zcnt, (uint32_t)(16 * 36));
  {
    const int wave = threadIdx.x >> 6, lane = threadIdx.x & 63;
    int b = slab * 64 + li * 4 + wave;
    const float* zr = z + (size_t)b * D_N;
    float ss = 0.f;
    for (int d = lane; d < D_N; d += 64) {
      float v = zr[d];
      out[(size_t)b * D_N + d] = v;
      ss += v * v;
    }
    for (int off = 32; off; off >>= 1) ss += __shfl_down(ss, off);
    if (lane == 0) out[BD + b] = -0.5f * ss + lp[b];
  }
}

// ---------------- fallback multi-launch kernels (R9-equivalent) ----------------
__global__ void k_keysched(uint32_t* __restrict__ ekeys) {
  if (threadIdx.x == 0 && blockIdx.x == 0) keysched_body(ekeys);
}
__global__ void kegen_g(u16* __restrict__ ebf, const uint32_t* __restrict__ keys) {
  int t = blockIdx.x * 256 + threadIdx.x;
  if (t < 36 * 65536) egen_item(t, ebf, keys);
}
__global__ void k_init(const float* __restrict__ x, float* __restrict__ z, u16* __restrict__ zin,
                       float* __restrict__ lp, float* __restrict__ d0, float* __restrict__ d1) {
  int i = blockIdx.x * 256 + threadIdx.x;
  if (i < BD) { float v = x[i]; z[i] = v; zin[i] = f2bf(v); }
  if (i < B_N) { lp[i] = 0.f; d0[i] = 0.f; d1[i] = 0.f; }
}
__global__ void k_cvtT(const float* __restrict__ src, u16* __restrict__ dst, int R, int C) {
  int i = blockIdx.x * 256 + threadIdx.x;
  if (i >= R * C) return;
  int c = i / R, r = i - c * R;
  dst[i] = f2bf(src[(size_t)r * C + c]);
}
__global__ void k_cvt(const float* __restrict__ src, u16* __restrict__ dst, int n) {
  int i = blockIdx.x * 256 + threadIdx.x;
  if (i < n) dst[i] = f2bf(src[i]);
}
__global__ void k_sentinel(float* __restrict__ out, int n) {
  int i = blockIdx.x * 256 + threadIdx.x;
  if (i < n) out[i] = 12345.0f;
}
__global__ __launch_bounds__(256) void kf1_g(
    const u16* zin, const u16* e0g, const u16* e1g, const u16* W1T, const u16* W2b,
    const float* b1v, const float* tw1v, float tstage,
    u16* hbuf, float* div0, float* div1) {
  __shared__ u16 S[2 * 10240];
  f1_tile(S, blockIdx.x, zin, e0g, e1g, W1T, W2b, b1v, tw1v, tstage, hbuf, div0, div1);
}
__global__ __launch_bounds__(256) void kf3_g(
    const u16* hbuf, const u16* W2T, const float* b2v,
    float* z, float* ACC, float* T, u16* zin, float dt, int st,
    float* lp, float* div0, float* div1, float wdt) {
  __shared__ u16 S[2 * 10240];
  f3_tile(S, blockIdx.x, hbuf, W2T, b2v, z, ACC, T, zin, dt, st, lp, div0, div1, wdt);
}
__global__ void k_out(const float* __restrict__ z, const float* __restrict__ lp,
                      float* __restrict__ out) {
  int b = blockIdx.x, t = threadIdx.x;
  const float* zr = z + (size_t)b * D_N;
  float ss = 0.f;
  for (int d = t; d < D_N; d += 256) {
    float v = zr[d];
    out[(size_t)b * D_N + d] = v;
    ss += v * v;
  }
  for (int off = 32; off > 0; off >>= 1) ss += __shfl_down(ss, off);
  __shared__ float red[4];
  if ((t & 63) == 0) red[t >> 6] = ss;
  __syncthreads();
  if (t == 0) out[(size_t)BD + b] = -0.5f * (red[0] + red[1] + red[2] + red[3]) + lp[b];
}

extern "C" void kernel_launch(void* const* d_in, const int* in_sizes, int n_in,
                              void* d_out, int out_size, void* d_ws, size_t ws_size,
                              hipStream_t stream) {
  const float* x   = (const float*)d_in[0];
  const float* W1  = (const float*)d_in[1];
  const float* b1  = (const float*)d_in[2];
  const float* tw1 = (const float*)d_in[3];
  const float* W2  = (const float*)d_in[4];
  const float* b2  = (const float*)d_in[5];
  float* outp = (float*)d_out;

  const size_t NEEDED = (size_t)180 << 20;
  if (ws_size < NEEDED) {
    k_sentinel<<<(BD + B_N + 255) / 256, 256, 0, stream>>>(outp, BD + B_N);
    return;
  }
  char* w = (char*)d_ws;
  auto carve = [&](size_t bytes) { char* p = w; w += (bytes + 255) & ~(size_t)255; return p; };
  uint32_t* bar  = (uint32_t*)carve(10240 * sizeof(uint32_t));    // gcnt/zcnt/hflag
  uint32_t* keys = (uint32_t*)carve(144 * sizeof(uint32_t));
  u16* ebf   = (u16*)carve((size_t)36 * 2 * BD * 2);              // 151 MB: all stages' e
  float* z   = (float*)carve((size_t)BD * 4);
  float* ACC = (float*)carve((size_t)BD * 4);
  float* T   = (float*)carve((size_t)BD * 4);
  u16* zin   = (u16*)carve((size_t)BD * 2);
  u16* hbuf  = (u16*)carve((size_t)B_N * H_N * 2);
  u16* W1T   = (u16*)carve((size_t)H_N * D_N * 2);
  u16* W2b   = (u16*)carve((size_t)H_N * D_N * 2);
  u16* W2T   = (u16*)carve((size_t)D_N * H_N * 2);
  float* lp   = (float*)carve((size_t)B_N * 4);
  float* div0 = (float*)carve((size_t)B_N * 4);
  float* div1 = (float*)carve((size_t)B_N * 4);

  // ---- try the persistent kernel (coop launch guarantees co-residency) ----
  int maxb = 0;
  hipError_t orc = hipOccupancyMaxActiveBlocksPerMultiprocessor(&maxb, (const void*)k_main, 256, 0);
  if (orc == hipSuccess && maxb >= 2) {
    hipMemsetAsync(bar, 0, 10240 * sizeof(uint32_t), stream);
    void* params[] = { (void*)&x, (void*)&W1, (void*)&b1, (void*)&tw1, (void*)&W2, (void*)&b2,
                       (void*)&outp, (void*)&keys, (void*)&ebf, (void*)&z, (void*)&ACC, (void*)&T,
                       (void*)&zin, (void*)&hbuf, (void*)&W1T, (void*)&W2b, (void*)&W2T,
                       (void*)&lp, (void*)&div0, (void*)&div1, (void*)&bar };
    hipError_t rc = hipLaunchCooperativeKernel((const void*)k_main, dim3(512), dim3(256),
                                               params, 0, stream);
    if (rc == hipSuccess) return;
    (void)hipGetLastError();
  }

  // ---- fallback: multi-launch path ----
  k_keysched<<<1, 1, 0, stream>>>(keys);
  k_init<<<BD / 256, 256, 0, stream>>>(x, z, zin, lp, div0, div1);
  k_cvtT<<<(D_N * H_N) / 256, 256, 0, stream>>>(W1, W1T, D_N, H_N);
  k_cvt <<<(H_N * D_N) / 256, 256, 0, stream>>>(W2, W2b, H_N * D_N);
  k_cvtT<<<(H_N * D_N) / 256, 256, 0, stream>>>(W2, W2T, H_N, D_N);
  kegen_g<<<(36 * 65536) / 256, 256, 0, stream>>>(ebf, keys);

  for (int s = 0; s < 9; ++s) {
    float t0 = (float)s / 9.0f;
    float t1 = (float)(s + 1) / 9.0f;
    float dt = t1 - t0;
    float tst[4] = { t0, t0 + dt / 3.0f, t0 + dt * 2.0f / 3.0f, t1 };
    float wts[4] = { 1.f, 3.f, 3.f, 1.f };
    for (int st = 0; st < 4; ++st) {
      const int sg = s * 4 + st;
      const u16* e0g = ebf + (size_t)sg * (2 * (size_t)BD);
      const u16* e1g = e0g + BD;
      kf1_g<<<512, 256, 0, stream>>>(zin, e0g, e1g, W1T, W2b, b1, tw1, tst[st], hbuf, div0, div1);
      kf3_g<<<512, 256, 0, stream>>>(hbuf, W2T, b2, z, ACC, T, zin, dt, st,
                                     lp, div0, div1, dt * 0.125f * wts[st]);
    }
  }
  k_out<<<B_N, 256, 0, stream>>>(z, lp, outp);
}

// Round 13
// 1497.889 us; speedup vs baseline: 3.7770x; 1.0498x over previous
//
#include <hip/hip_runtime.h>
#include <stdint.h>

// FFJORD block: B=2048, D=512, H=1024, 9 RK38 steps x 4 stages, 2 Hutchinson probes.
// f32 in/out. bf16 MFMA GEMMs, f32 accumulate, fp32 RK state.
// PRNG: JAX threefry partitionable (verified R7).
// R13: back to multi-launch (persistent lost 3x: R10-R12). New: XOR-swizzled LDS
// layout kills the 8-way bank conflicts on every ds_read_b128 (R12 profile:
// SQ_LDS_BANK_CONFLICT=7.5e7). Source col ^= (srow>>1)&3 at DMA; fragment reads
// use chunk q ^ ((row>>1)&3). 512-block f3 (64x32 tiles); fast_tanh.

#define B_N 2048
#define D_N 512
#define H_N 1024
#define BD (B_N * D_N)

typedef unsigned short u16;
typedef __attribute__((ext_vector_type(8))) short s16x8;   // 8 x bf16
typedef __attribute__((ext_vector_type(4))) float f32x4;   // MFMA accumulator

typedef __attribute__((address_space(1))) const uint32_t ga_u32;
typedef __attribute__((address_space(3))) uint32_t ls_u32;

#if __has_builtin(__builtin_amdgcn_alignbit)
#define ROTL32(x, r) __builtin_amdgcn_alignbit((x), (x), 32 - (r))
#else
#define ROTL32(x, r) (((x) << (r)) | ((x) >> (32 - (r))))
#endif

__device__ __forceinline__ u16 f2bf(float f) {
  union { float f; uint32_t u; } c; c.f = f;
  uint32_t r = c.u + 0x7FFFu + ((c.u >> 16) & 1u);  // RTNE
  return (u16)(r >> 16);
}
__device__ __forceinline__ float fast_tanh(float v) {
  float e = __expf(2.0f * fabsf(v));
  float t = 1.0f - 2.0f / (e + 1.0f);
  return copysignf(t, v);
}

struct U2 { uint32_t x, y; };

// Threefry-2x32, 20 rounds — KAT-verified.
__device__ __forceinline__ U2 tf2x32(uint32_t k0, uint32_t k1, uint32_t x0, uint32_t x1) {
  uint32_t k2 = k0 ^ k1 ^ 0x1BD11BDAu;
#define RND(r) { x0 += x1; x1 = ROTL32(x1, r); x1 ^= x0; }
  x0 += k0; x1 += k1;
  RND(13) RND(15) RND(26) RND(6)
  x0 += k1; x1 += k2 + 1u;
  RND(17) RND(29) RND(16) RND(24)
  x0 += k2; x1 += k0 + 2u;
  RND(13) RND(15) RND(26) RND(6)
  x0 += k0; x1 += k1 + 3u;
  RND(17) RND(29) RND(16) RND(24)
  x0 += k1; x1 += k2 + 4u;
  RND(13) RND(15) RND(26) RND(6)
  x0 += k2; x1 += k0 + 5u;
#undef RND
  U2 r; r.x = x0; r.y = x1; return r;
}

// Partitionable key schedule (verified R7).
__global__ void k_keysched(uint32_t* __restrict__ ekeys) {
  if (threadIdx.x != 0 || blockIdx.x != 0) return;
  uint32_t kx = 0u, ky = 1234u;
  for (int s = 0; s < 9; ++s) {
    for (int st = 0; st < 4; ++st) {
      U2 kst = tf2x32(kx, ky, 0u, (uint32_t)(st + 1));
      for (int pr = 0; pr < 2; ++pr) {
        U2 fo = tf2x32(kst.x, kst.y, 0u, (uint32_t)pr);
        U2 k2 = tf2x32(fo.x, fo.y, 0u, 1u);
        ekeys[(s * 4 + st) * 4 + pr * 2 + 0] = k2.x;
        ekeys[(s * 4 + st) * 4 + pr * 2 + 1] = k2.y;
      }
    }
    U2 c = tf2x32(kx, ky, 0u, 0u);
    kx = c.x; ky = c.y;
  }
}

// Fused threefry + bf16 +-1 expansion for a group of 4 stages (ring of 4 slots).
// e_p = lsb(x^y) of tf(k2, (0,p)).
__global__ void k_egen(u16* __restrict__ ebf, const uint32_t* __restrict__ keys, int gs) {
  int t = blockIdx.x * 256 + threadIdx.x;   // 262144 threads
  int stage = gs + (t >> 16), rem = t & 65535;
  int probe = rem >> 15, idx = rem & 32767;
  uint32_t p0 = (uint32_t)idx * 32;
  uint32_t k0 = keys[stage * 4 + probe * 2], k1 = keys[stage * 4 + probe * 2 + 1];
  uint4* dst = (uint4*)(ebf + (size_t)(stage & 3) * (2 * (size_t)BD) + (size_t)probe * BD + (size_t)idx * 32);
#pragma unroll
  for (int g = 0; g < 4; ++g) {
    uint32_t pr[4];
#pragma unroll
    for (int h = 0; h < 4; ++h) {
      uint32_t c0 = p0 + g * 8 + h * 2;
      U2 r0 = tf2x32(k0, k1, 0u, c0);
      U2 r1 = tf2x32(k0, k1, 0u, c0 + 1u);
      pr[h] = (((r0.x ^ r0.y) & 1u) ? 0x3F80u : 0xBF80u) |
              (((r1.x ^ r1.y) & 1u) ? 0x3F800000u : 0xBF800000u);
    }
    uint4 v; v.x = pr[0]; v.y = pr[1]; v.z = pr[2]; v.w = pr[3];
    dst[g] = v;
  }
}

__global__ void k_init(const float* __restrict__ x, float* __restrict__ z, u16* __restrict__ zin,
                       float* __restrict__ lp, float* __restrict__ d0, float* __restrict__ d1) {
  int i = blockIdx.x * 256 + threadIdx.x;
  if (i < BD) { float v = x[i]; z[i] = v; zin[i] = f2bf(v); }
  if (i < B_N) { lp[i] = 0.f; d0[i] = 0.f; d1[i] = 0.f; }
}

__global__ void k_cvtT(const float* __restrict__ src, u16* __restrict__ dst, int R, int C) {
  int i = blockIdx.x * 256 + threadIdx.x;
  if (i >= R * C) return;
  int c = i / R, r = i - c * R;
  dst[i] = f2bf(src[(size_t)r * C + c]);
}
__global__ void k_cvt(const float* __restrict__ src, u16* __restrict__ dst, int n) {
  int i = blockIdx.x * 256 + threadIdx.x;
  if (i < n) dst[i] = f2bf(src[i]);
}

__global__ void k_sentinel(float* __restrict__ out, int n) {
  int i = blockIdx.x * 256 + threadIdx.x;
  if (i < n) out[i] = 12345.0f;
}

// LDS chunk swizzle: data chunk c of row r lives at LDS chunk c ^ ((r>>1)&3).
// DMA side stages source chunk (lane&3)^((srow>>1)&3) at lane-implicit dst.
// Read side fetches chunk q^((row>>1)&3). 32-lane b128 then hits every bank
// group exactly 4x = conflict-free floor.

// Fused 5-product GEMM, 64x64 tiles, K=512. Double-buffered DMA + swizzle.
__global__ __launch_bounds__(256)
void k_f1(const u16* __restrict__ zin, const u16* __restrict__ e0g, const u16* __restrict__ e1g,
          const u16* __restrict__ W1T, const u16* __restrict__ W2b,
          const float* __restrict__ b1v, const float* __restrict__ tw1v, float tstage,
          u16* __restrict__ hbuf, float* __restrict__ div0, float* __restrict__ div1) {
  __shared__ u16 S[2][5 * 2048];
  const int tid = threadIdx.x, wave = tid >> 6, lane = tid & 63;
  const int bm = blockIdx.x >> 4;
  const int bh = blockIdx.x & 15;
  const int row0 = bm * 64, col0 = bh * 64;
  const int wm = wave >> 1, wn = wave & 1, r16 = lane & 15, q = lane >> 4;
  const int srow = lane >> 2;
  const int scol = (((lane & 3) ^ ((srow >> 1) & 3))) * 8;   // swizzled source chunk
  const int cqa = (q ^ ((r16 >> 1) & 3)) * 8;                // swizzled read chunk

  f32x4 az[2][2], au0[2][2], au1[2][2], av0[2][2], av1[2][2];
#pragma unroll
  for (int i = 0; i < 2; ++i)
#pragma unroll
    for (int j = 0; j < 2; ++j) {
      az[i][j] = (f32x4){0,0,0,0}; au0[i][j] = (f32x4){0,0,0,0}; au1[i][j] = (f32x4){0,0,0,0};
      av0[i][j] = (f32x4){0,0,0,0}; av1[i][j] = (f32x4){0,0,0,0};
    }

  const size_t arow = (size_t)(row0 + wave * 16 + srow) * 512 + scol;
  const size_t brow = (size_t)(col0 + wave * 16 + srow) * 512 + scol;
  auto stage = [&](int kt, int buf) {
    u16* b = &S[buf][0];
    __builtin_amdgcn_global_load_lds((ga_u32*)(zin + arow + kt), (ls_u32*)(b + 0    + wave * 512), 16, 0, 0);
    __builtin_amdgcn_global_load_lds((ga_u32*)(e0g + arow + kt), (ls_u32*)(b + 2048 + wave * 512), 16, 0, 0);
    __builtin_amdgcn_global_load_lds((ga_u32*)(e1g + arow + kt), (ls_u32*)(b + 4096 + wave * 512), 16, 0, 0);
    __builtin_amdgcn_global_load_lds((ga_u32*)(W1T + brow + kt), (ls_u32*)(b + 6144 + wave * 512), 16, 0, 0);
    __builtin_amdgcn_global_load_lds((ga_u32*)(W2b + brow + kt), (ls_u32*)(b + 8192 + wave * 512), 16, 0, 0);
  };
  stage(0, 0);
  for (int it = 0; it < 16; ++it) {
    const int buf = it & 1;
    __syncthreads();
    if (it + 1 < 16) stage((it + 1) * 32, buf ^ 1);
    const u16* b = &S[buf][0];
    s16x8 zf[2], e0f[2], e1f[2], w1f[2], w2f[2];
#pragma unroll
    for (int i = 0; i < 2; ++i) {
      const int ao = (wm * 32 + i * 16 + r16) * 32 + cqa;
      zf[i]  = *(const s16x8*)(b + 0    + ao);
      e0f[i] = *(const s16x8*)(b + 2048 + ao);
      e1f[i] = *(const s16x8*)(b + 4096 + ao);
    }
#pragma unroll
    for (int j = 0; j < 2; ++j) {
      const int bo = (wn * 32 + j * 16 + r16) * 32 + cqa;
      w1f[j] = *(const s16x8*)(b + 6144 + bo);
      w2f[j] = *(const s16x8*)(b + 8192 + bo);
    }
#pragma unroll
    for (int i = 0; i < 2; ++i)
#pragma unroll
      for (int j = 0; j < 2; ++j) {
        az[i][j]  = __builtin_amdgcn_mfma_f32_16x16x32_bf16(zf[i],  w1f[j], az[i][j],  0, 0, 0);
        au0[i][j] = __builtin_amdgcn_mfma_f32_16x16x32_bf16(e0f[i], w1f[j], au0[i][j], 0, 0, 0);
        au1[i][j] = __builtin_amdgcn_mfma_f32_16x16x32_bf16(e1f[i], w1f[j], au1[i][j], 0, 0, 0);
        av0[i][j] = __builtin_amdgcn_mfma_f32_16x16x32_bf16(e0f[i], w2f[j], av0[i][j], 0, 0, 0);
        av1[i][j] = __builtin_amdgcn_mfma_f32_16x16x32_bf16(e1f[i], w2f[j], av1[i][j], 0, 0, 0);
      }
  }

  float d0s[2][4], d1s[2][4];
#pragma unroll
  for (int i = 0; i < 2; ++i)
#pragma unroll
    for (int r = 0; r < 4; ++r) { d0s[i][r] = 0.f; d1s[i][r] = 0.f; }

#pragma unroll
  for (int j = 0; j < 2; ++j) {
    const int gcol = col0 + wn * 32 + j * 16 + r16;
    const float colb = b1v[gcol] + tstage * tw1v[gcol];
#pragma unroll
    for (int i = 0; i < 2; ++i) {
      const int rbase = row0 + wm * 32 + i * 16 + q * 4;   // C/D: row=quad*4+reg
#pragma unroll
      for (int r = 0; r < 4; ++r) {
        float hv = fast_tanh(az[i][j][r] + colb);
        hbuf[(size_t)(rbase + r) * H_N + gcol] = f2bf(hv);
        float s = 1.f - hv * hv;
        d0s[i][r] += s * au0[i][j][r] * av0[i][j][r];
        d1s[i][r] += s * au1[i][j][r] * av1[i][j][r];
      }
    }
  }
#pragma unroll
  for (int i = 0; i < 2; ++i)
#pragma unroll
    for (int r = 0; r < 4; ++r) {
      float a = d0s[i][r], bb = d1s[i][r];
#pragma unroll
      for (int m = 1; m < 16; m <<= 1) { a += __shfl_xor(a, m); bb += __shfl_xor(bb, m); }
      if (r16 == 0) {
        int grow = row0 + wm * 32 + i * 16 + q * 4 + r;
        atomicAdd(&div0[grow], a);
        atomicAdd(&div1[grow], bb);
      }
    }
}

// GEMM3 (f = h@W2 + b2), 64x32 tiles (512 blocks), K=1024; RK38 epilogue +
// fused divapply (bn==0). Double-buffered DMA + swizzle.
template<int ST>
__global__ __launch_bounds__(256)
void k_f3(const u16* __restrict__ hbuf, const u16* __restrict__ W2T, const float* __restrict__ b2v,
          float* __restrict__ z, float* __restrict__ ACC, float* __restrict__ T,
          u16* __restrict__ zin, float dt,
          float* __restrict__ lp, float* __restrict__ div0, float* __restrict__ div1, float wdt) {
  __shared__ u16 S[2][3 * 2048];   // per buf: A(64x32)=2048*2? -> A:4096? see layout below
  // layout per buf (u16): A[64x32]=2048? 64*32=2048. B[32x32]=1024. total 3072; use 3*2048 pad.
  const int tid = threadIdx.x, wave = tid >> 6, lane = tid & 63;
  const int bm = blockIdx.x >> 4;
  const int bn = blockIdx.x & 15;
  const int row0 = bm * 64, col0 = bn * 32;
  const int r16 = lane & 15, q = lane >> 4;
  const int srow = lane >> 2;
  const int scol = (((lane & 3) ^ ((srow >> 1) & 3))) * 8;
  const int cqa = (q ^ ((r16 >> 1) & 3)) * 8;

  if (bn == 0 && tid < 64) {
    int b = row0 + tid;
    float c = 0.5f * (div0[b] + div1[b]);
    c = fminf(fmaxf(c, -100.f), 100.f);
    lp[b] -= wdt * c;
    div0[b] = 0.f; div1[b] = 0.f;
  }

  f32x4 acc[2];
  acc[0] = (f32x4){0,0,0,0}; acc[1] = (f32x4){0,0,0,0};

  const size_t arow = (size_t)(row0 + wave * 16 + srow) * 1024 + scol;
  const size_t brow = (size_t)(col0 + (wave & 1) * 16 + srow) * 1024 + scol;
  auto stage = [&](int kt, int buf) {
    u16* b = &S[buf][0];
    __builtin_amdgcn_global_load_lds((ga_u32*)(hbuf + arow + kt), (ls_u32*)(b + wave * 512), 16, 0, 0);
    if (wave < 2)
      __builtin_amdgcn_global_load_lds((ga_u32*)(W2T + brow + kt), (ls_u32*)(b + 4096 + wave * 512), 16, 0, 0);
  };
  stage(0, 0);
  for (int it = 0; it < 32; ++it) {
    const int buf = it & 1;
    __syncthreads();
    if (it + 1 < 32) stage((it + 1) * 32, buf ^ 1);
    const u16* b = &S[buf][0];
    s16x8 af  = *(const s16x8*)(b + (wave * 16 + r16) * 32 + cqa);
    s16x8 bf0 = *(const s16x8*)(b + 4096 + r16 * 32 + cqa);
    s16x8 bf1 = *(const s16x8*)(b + 4096 + (16 + r16) * 32 + cqa);
    acc[0] = __builtin_amdgcn_mfma_f32_16x16x32_bf16(af, bf0, acc[0], 0, 0, 0);
    acc[1] = __builtin_amdgcn_mfma_f32_16x16x32_bf16(af, bf1, acc[1], 0, 0, 0);
  }

#pragma unroll
  for (int j = 0; j < 2; ++j) {
    const int gcol = col0 + j * 16 + r16;
    const float cb = b2v[gcol];
    const int rbase = row0 + wave * 16 + q * 4;
#pragma unroll
    for (int r = 0; r < 4; ++r) {
      const size_t idx = (size_t)(rbase + r) * D_N + gcol;
      const float f = acc[j][r] + cb;
      if (ST == 0) {
        ACC[idx] = dt * 0.125f * f;
        T[idx]   = dt * f;
        zin[idx] = f2bf(z[idx] + dt * f * (1.f / 3.f));
      } else if (ST == 1) {
        float t_ = T[idx];
        ACC[idx] += 0.375f * dt * f;
        zin[idx] = f2bf(z[idx] + dt * f - t_ * (1.f / 3.f));
        T[idx]   = t_ - dt * f;
      } else if (ST == 2) {
        ACC[idx] += 0.375f * dt * f;
        zin[idx] = f2bf(z[idx] + T[idx] + dt * f);
      } else {
        float zn = z[idx] + ACC[idx] + dt * 0.125f * f;
        z[idx]   = zn;
        zin[idx] = f2bf(zn);
      }
    }
  }
}

// out = [rep (f32, BxD) ; logprob (f32, B)]
__global__ void k_out(const float* __restrict__ z, const float* __restrict__ lp,
                      float* __restrict__ out) {
  int b = blockIdx.x, t = threadIdx.x;
  const float* zr = z + (size_t)b * D_N;
  float ss = 0.f;
  for (int d = t; d < D_N; d += 256) {
    float v = zr[d];
    out[(size_t)b * D_N + d] = v;
    ss += v * v;
  }
  for (int off = 32; off > 0; off >>= 1) ss += __shfl_down(ss, off);
  __shared__ float red[4];
  if ((t & 63) == 0) red[t >> 6] = ss;
  __syncthreads();
  if (t == 0) out[(size_t)BD + b] = -0.5f * (red[0] + red[1] + red[2] + red[3]) + lp[b];
}

extern "C" void kernel_launch(void* const* d_in, const int* in_sizes, int n_in,
                              void* d_out, int out_size, void* d_ws, size_t ws_size,
                              hipStream_t stream) {
  const float* x   = (const float*)d_in[0];
  const float* W1  = (const float*)d_in[1];
  const float* b1  = (const float*)d_in[2];
  const float* tw1 = (const float*)d_in[3];
  const float* W2  = (const float*)d_in[4];
  const float* b2  = (const float*)d_in[5];
  float* outp = (float*)d_out;

  const size_t NEEDED = (size_t)45 << 20;
  if (ws_size < NEEDED) {
    k_sentinel<<<(BD + B_N + 255) / 256, 256, 0, stream>>>(outp, BD + B_N);
    return;
  }
  char* w = (char*)d_ws;
  auto carve = [&](size_t bytes) { char* p = w; w += (bytes + 255) & ~(size_t)255; return p; };
  uint32_t* keys = (uint32_t*)carve(144 * sizeof(uint32_t));
  u16* ebf   = (u16*)carve((size_t)4 * 2 * BD * 2);               // 16 MB: 4-slot e ring
  float* z   = (float*)carve((size_t)BD * 4);
  float* ACC = (float*)carve((size_t)BD * 4);
  float* T   = (float*)carve((size_t)BD * 4);
  u16* zin   = (u16*)carve((size_t)BD * 2);
  u16* hbuf  = (u16*)carve((size_t)B_N * H_N * 2);
  u16* W1T   = (u16*)carve((size_t)H_N * D_N * 2);
  u16* W2b   = (u16*)carve((size_t)H_N * D_N * 2);
  u16* W2T   = (u16*)carve((size_t)D_N * H_N * 2);
  float* lp   = (float*)carve((size_t)B_N * 4);
  float* div0 = (float*)carve((size_t)B_N * 4);
  float* div1 = (float*)carve((size_t)B_N * 4);

  k_keysched<<<1, 1, 0, stream>>>(keys);
  k_init<<<BD / 256, 256, 0, stream>>>(x, z, zin, lp, div0, div1);
  k_cvtT<<<(D_N * H_N) / 256, 256, 0, stream>>>(W1, W1T, D_N, H_N);
  k_cvt <<<(H_N * D_N) / 256, 256, 0, stream>>>(W2, W2b, H_N * D_N);
  k_cvtT<<<(H_N * D_N) / 256, 256, 0, stream>>>(W2, W2T, H_N, D_N);

  const int gF1 = (B_N / 64) * (H_N / 64);   // 512
  const int gF3 = (B_N / 64) * (D_N / 32);   // 512

  for (int s = 0; s < 9; ++s) {
    float t0 = (float)s / 9.0f;
    float t1 = (float)(s + 1) / 9.0f;
    float dt = t1 - t0;
    float tst[4] = { t0, t0 + dt / 3.0f, t0 + dt * 2.0f / 3.0f, t1 };
    float wts[4] = { 1.f, 3.f, 3.f, 1.f };
    for (int st = 0; st < 4; ++st) {
      const int sg = s * 4 + st;
      if ((sg & 3) == 0) k_egen<<<1024, 256, 0, stream>>>(ebf, keys, sg);
      const u16* e0g = ebf + (size_t)(sg & 3) * (2 * (size_t)BD);
      const u16* e1g = e0g + BD;
      k_f1<<<gF1, 256, 0, stream>>>(zin, e0g, e1g, W1T, W2b, b1, tw1, tst[st], hbuf, div0, div1);
      const float wdt = dt * 0.125f * wts[st];
      if (st == 0)      k_f3<0><<<gF3, 256, 0, stream>>>(hbuf, W2T, b2, z, ACC, T, zin, dt, lp, div0, div1, wdt);
      else if (st == 1) k_f3<1><<<gF3, 256, 0, stream>>>(hbuf, W2T, b2, z, ACC, T, zin, dt, lp, div0, div1, wdt);
      else if (st == 2) k_f3<2><<<gF3, 256, 0, stream>>>(hbuf, W2T, b2, z, ACC, T, zin, dt, lp, div0, div1, wdt);
      else              k_f3<3><<<gF3, 256, 0, stream>>>(hbuf, W2T, b2, z, ACC, T, zin, dt, lp, div0, div1, wdt);
    }
  }
  k_out<<<B_N, 256, 0, stream>>>(z, lp, outp);
}

// Round 14
// 1400.986 us; speedup vs baseline: 4.0383x; 1.0692x over previous
//
#include <hip/hip_runtime.h>
#include <stdint.h>

// FFJORD block: B=2048, D=512, H=1024, 9 RK38 steps x 4 stages, 2 Hutchinson probes.
// f32 in/out. bf16 MFMA GEMMs, f32 accumulate, fp32 RK state.
// PRNG: JAX threefry partitionable (verified R7).
// R14: XCD-affinity scheduling. Evidence R11-R13: per-stage ~34us invariant to
// sync mechanism => LLC-BW bound on cross-XCD tile traffic (f1 164MB + f3 98MB
// per dispatch through Infinity Cache). Fix: pin each 64-row slab to one XCD
// via blockIdx%8 (slab = xcd*4 + hi-bits) in f1/f3/egen/out so zin/hbuf/e/div
// stay in the producing XCD's 4MB L2. Else identical to R13 (swizzled LDS).

#define B_N 2048
#define D_N 512
#define H_N 1024
#define BD (B_N * D_N)

typedef unsigned short u16;
typedef __attribute__((ext_vector_type(8))) short s16x8;   // 8 x bf16
typedef __attribute__((ext_vector_type(4))) float f32x4;   // MFMA accumulator

typedef __attribute__((address_space(1))) const uint32_t ga_u32;
typedef __attribute__((address_space(3))) uint32_t ls_u32;

#if __has_builtin(__builtin_amdgcn_alignbit)
#define ROTL32(x, r) __builtin_amdgcn_alignbit((x), (x), 32 - (r))
#else
#define ROTL32(x, r) (((x) << (r)) | ((x) >> (32 - (r))))
#endif

__device__ __forceinline__ u16 f2bf(float f) {
  union { float f; uint32_t u; } c; c.f = f;
  uint32_t r = c.u + 0x7FFFu + ((c.u >> 16) & 1u);  // RTNE
  return (u16)(r >> 16);
}
__device__ __forceinline__ float fast_tanh(float v) {
  float e = __expf(2.0f * fabsf(v));
  float t = 1.0f - 2.0f / (e + 1.0f);
  return copysignf(t, v);
}

struct U2 { uint32_t x, y; };

// Threefry-2x32, 20 rounds — KAT-verified.
__device__ __forceinline__ U2 tf2x32(uint32_t k0, uint32_t k1, uint32_t x0, uint32_t x1) {
  uint32_t k2 = k0 ^ k1 ^ 0x1BD11BDAu;
#define RND(r) { x0 += x1; x1 = ROTL32(x1, r); x1 ^= x0; }
  x0 += k0; x1 += k1;
  RND(13) RND(15) RND(26) RND(6)
  x0 += k1; x1 += k2 + 1u;
  RND(17) RND(29) RND(16) RND(24)
  x0 += k2; x1 += k0 + 2u;
  RND(13) RND(15) RND(26) RND(6)
  x0 += k0; x1 += k1 + 3u;
  RND(17) RND(29) RND(16) RND(24)
  x0 += k1; x1 += k2 + 4u;
  RND(13) RND(15) RND(26) RND(6)
  x0 += k2; x1 += k0 + 5u;
#undef RND
  U2 r; r.x = x0; r.y = x1; return r;
}

// Partitionable key schedule (verified R7).
__global__ void k_keysched(uint32_t* __restrict__ ekeys) {
  if (threadIdx.x != 0 || blockIdx.x != 0) return;
  uint32_t kx = 0u, ky = 1234u;
  for (int s = 0; s < 9; ++s) {
    for (int st = 0; st < 4; ++st) {
      U2 kst = tf2x32(kx, ky, 0u, (uint32_t)(st + 1));
      for (int pr = 0; pr < 2; ++pr) {
        U2 fo = tf2x32(kst.x, kst.y, 0u, (uint32_t)pr);
        U2 k2 = tf2x32(fo.x, fo.y, 0u, 1u);
        ekeys[(s * 4 + st) * 4 + pr * 2 + 0] = k2.x;
        ekeys[(s * 4 + st) * 4 + pr * 2 + 1] = k2.y;
      }
    }
    U2 c = tf2x32(kx, ky, 0u, 0u);
    kx = c.x; ky = c.y;
  }
}

// Fused threefry + bf16 expansion for 4 stages, XCD-affine: slab data is
// generated by blocks on the XCD (blockIdx&7) that will consume it.
// e_p = lsb(x^y) of tf(k2, (0,p)).
__global__ void k_egen(u16* __restrict__ ebf, const uint32_t* __restrict__ keys, int gs) {
  const int xcd = blockIdx.x & 7, bi = blockIdx.x >> 3;      // 1024 blocks: 128/XCD
  const int u = bi * 256 + threadIdx.x;                       // 0..32767 per XCD
  const int slab = xcd * 4 + (u >> 13);
  const int r13 = u & 8191;
  const int stage = gs + (r13 >> 11);
  const int r11 = r13 & 2047;
  const int probe = r11 >> 10;
  const int unit = r11 & 1023;                                // 1024 units/slab
  const uint32_t p0 = (uint32_t)(slab * 32768 + unit * 32);
  uint32_t k0 = keys[stage * 4 + probe * 2], k1 = keys[stage * 4 + probe * 2 + 1];
  uint4* dst = (uint4*)(ebf + (size_t)(stage & 3) * (2 * (size_t)BD) + (size_t)probe * BD + (size_t)p0);
#pragma unroll
  for (int g = 0; g < 4; ++g) {
    uint32_t pr[4];
#pragma unroll
    for (int h = 0; h < 4; ++h) {
      uint32_t c0 = p0 + g * 8 + h * 2;
      U2 r0 = tf2x32(k0, k1, 0u, c0);
      U2 r1 = tf2x32(k0, k1, 0u, c0 + 1u);
      pr[h] = (((r0.x ^ r0.y) & 1u) ? 0x3F80u : 0xBF80u) |
              (((r1.x ^ r1.y) & 1u) ? 0x3F800000u : 0xBF800000u);
    }
    uint4 v; v.x = pr[0]; v.y = pr[1]; v.z = pr[2]; v.w = pr[3];
    dst[g] = v;
  }
}

__global__ void k_init(const float* __restrict__ x, float* __restrict__ z, u16* __restrict__ zin,
                       float* __restrict__ lp, float* __restrict__ d0, float* __restrict__ d1) {
  int i = blockIdx.x * 256 + threadIdx.x;
  if (i < BD) { float v = x[i]; z[i] = v; zin[i] = f2bf(v); }
  if (i < B_N) { lp[i] = 0.f; d0[i] = 0.f; d1[i] = 0.f; }
}

__global__ void k_cvtT(const float* __restrict__ src, u16* __restrict__ dst, int R, int C) {
  int i = blockIdx.x * 256 + threadIdx.x;
  if (i >= R * C) return;
  int c = i / R, r = i - c * R;
  dst[i] = f2bf(src[(size_t)r * C + c]);
}
__global__ void k_cvt(const float* __restrict__ src, u16* __restrict__ dst, int n) {
  int i = blockIdx.x * 256 + threadIdx.x;
  if (i < n) dst[i] = f2bf(src[i]);
}

__global__ void k_sentinel(float* __restrict__ out, int n) {
  int i = blockIdx.x * 256 + threadIdx.x;
  if (i < n) out[i] = 12345.0f;
}

// LDS chunk swizzle (R13-verified): chunk c of row r at LDS chunk c^((r>>1)&3).

// Fused 5-product GEMM, 64x64 tiles, K=512. XCD-affine: slab = (bid&7)*4+((bid>>3)>>4).
__global__ __launch_bounds__(256)
void k_f1(const u16* __restrict__ zin, const u16* __restrict__ e0g, const u16* __restrict__ e1g,
          const u16* __restrict__ W1T, const u16* __restrict__ W2b,
          const float* __restrict__ b1v, const float* __restrict__ tw1v, float tstage,
          u16* __restrict__ hbuf, float* __restrict__ div0, float* __restrict__ div1) {
  __shared__ u16 S[2][5 * 2048];
  const int tid = threadIdx.x, wave = tid >> 6, lane = tid & 63;
  const int xcd = blockIdx.x & 7, idx = blockIdx.x >> 3;
  const int bm = xcd * 4 + (idx >> 4);       // slab pinned to XCD
  const int bh = idx & 15;
  const int row0 = bm * 64, col0 = bh * 64;
  const int wm = wave >> 1, wn = wave & 1, r16 = lane & 15, q = lane >> 4;
  const int srow = lane >> 2;
  const int scol = (((lane & 3) ^ ((srow >> 1) & 3))) * 8;   // swizzled source chunk
  const int cqa = (q ^ ((r16 >> 1) & 3)) * 8;                // swizzled read chunk

  f32x4 az[2][2], au0[2][2], au1[2][2], av0[2][2], av1[2][2];
#pragma unroll
  for (int i = 0; i < 2; ++i)
#pragma unroll
    for (int j = 0; j < 2; ++j) {
      az[i][j] = (f32x4){0,0,0,0}; au0[i][j] = (f32x4){0,0,0,0}; au1[i][j] = (f32x4){0,0,0,0};
      av0[i][j] = (f32x4){0,0,0,0}; av1[i][j] = (f32x4){0,0,0,0};
    }

  const size_t arow = (size_t)(row0 + wave * 16 + srow) * 512 + scol;
  const size_t brow = (size_t)(col0 + wave * 16 + srow) * 512 + scol;
  auto stage = [&](int kt, int buf) {
    u16* b = &S[buf][0];
    __builtin_amdgcn_global_load_lds((ga_u32*)(zin + arow + kt), (ls_u32*)(b + 0    + wave * 512), 16, 0, 0);
    __builtin_amdgcn_global_load_lds((ga_u32*)(e0g + arow + kt), (ls_u32*)(b + 2048 + wave * 512), 16, 0, 0);
    __builtin_amdgcn_global_load_lds((ga_u32*)(e1g + arow + kt), (ls_u32*)(b + 4096 + wave * 512), 16, 0, 0);
    __builtin_amdgcn_global_load_lds((ga_u32*)(W1T + brow + kt), (ls_u32*)(b + 6144 + wave * 512), 16, 0, 0);
    __builtin_amdgcn_global_load_lds((ga_u32*)(W2b + brow + kt), (ls_u32*)(b + 8192 + wave * 512), 16, 0, 0);
  };
  stage(0, 0);
  for (int it = 0; it < 16; ++it) {
    const int buf = it & 1;
    __syncthreads();
    if (it + 1 < 16) stage((it + 1) * 32, buf ^ 1);
    const u16* b = &S[buf][0];
    s16x8 zf[2], e0f[2], e1f[2], w1f[2], w2f[2];
#pragma unroll
    for (int i = 0; i < 2; ++i) {
      const int ao = (wm * 32 + i * 16 + r16) * 32 + cqa;
      zf[i]  = *(const s16x8*)(b + 0    + ao);
      e0f[i] = *(const s16x8*)(b + 2048 + ao);
      e1f[i] = *(const s16x8*)(b + 4096 + ao);
    }
#pragma unroll
    for (int j = 0; j < 2; ++j) {
      const int bo = (wn * 32 + j * 16 + r16) * 32 + cqa;
      w1f[j] = *(const s16x8*)(b + 6144 + bo);
      w2f[j] = *(const s16x8*)(b + 8192 + bo);
    }
#pragma unroll
    for (int i = 0; i < 2; ++i)
#pragma unroll
      for (int j = 0; j < 2; ++j) {
        az[i][j]  = __builtin_amdgcn_mfma_f32_16x16x32_bf16(zf[i],  w1f[j], az[i][j],  0, 0, 0);
        au0[i][j] = __builtin_amdgcn_mfma_f32_16x16x32_bf16(e0f[i], w1f[j], au0[i][j], 0, 0, 0);
        au1[i][j] = __builtin_amdgcn_mfma_f32_16x16x32_bf16(e1f[i], w1f[j], au1[i][j], 0, 0, 0);
        av0[i][j] = __builtin_amdgcn_mfma_f32_16x16x32_bf16(e0f[i], w2f[j], av0[i][j], 0, 0, 0);
        av1[i][j] = __builtin_amdgcn_mfma_f32_16x16x32_bf16(e1f[i], w2f[j], av1[i][j], 0, 0, 0);
      }
  }

  float d0s[2][4], d1s[2][4];
#pragma unroll
  for (int i = 0; i < 2; ++i)
#pragma unroll
    for (int r = 0; r < 4; ++r) { d0s[i][r] = 0.f; d1s[i][r] = 0.f; }

#pragma unroll
  for (int j = 0; j < 2; ++j) {
    const int gcol = col0 + wn * 32 + j * 16 + r16;
    const float colb = b1v[gcol] + tstage * tw1v[gcol];
#pragma unroll
    for (int i = 0; i < 2; ++i) {
      const int rbase = row0 + wm * 32 + i * 16 + q * 4;   // C/D: row=quad*4+reg
#pragma unroll
      for (int r = 0; r < 4; ++r) {
        float hv = fast_tanh(az[i][j][r] + colb);
        hbuf[(size_t)(rbase + r) * H_N + gcol] = f2bf(hv);
        float s = 1.f - hv * hv;
        d0s[i][r] += s * au0[i][j][r] * av0[i][j][r];
        d1s[i][r] += s * au1[i][j][r] * av1[i][j][r];
      }
    }
  }
#pragma unroll
  for (int i = 0; i < 2; ++i)
#pragma unroll
    for (int r = 0; r < 4; ++r) {
      float a = d0s[i][r], bb = d1s[i][r];
#pragma unroll
      for (int m = 1; m < 16; m <<= 1) { a += __shfl_xor(a, m); bb += __shfl_xor(bb, m); }
      if (r16 == 0) {
        int grow = row0 + wm * 32 + i * 16 + q * 4 + r;
        atomicAdd(&div0[grow], a);
        atomicAdd(&div1[grow], bb);
      }
    }
}

// GEMM3 (f = h@W2 + b2), 64x32 tiles, K=1024; RK38 epilogue + fused divapply.
// XCD-affine: same slab mapping as f1 so hbuf/z/ACC/T/zin stay in-XCD.
template<int ST>
__global__ __launch_bounds__(256)
void k_f3(const u16* __restrict__ hbuf, const u16* __restrict__ W2T, const float* __restrict__ b2v,
          float* __restrict__ z, float* __restrict__ ACC, float* __restrict__ T,
          u16* __restrict__ zin, float dt,
          float* __restrict__ lp, float* __restrict__ div0, float* __restrict__ div1, float wdt) {
  __shared__ u16 S[2][3 * 2048];
  const int tid = threadIdx.x, wave = tid >> 6, lane = tid & 63;
  const int xcd = blockIdx.x & 7, idx = blockIdx.x >> 3;
  const int bm = xcd * 4 + (idx >> 4);       // slab pinned to XCD (matches f1)
  const int bn = idx & 15;
  const int row0 = bm * 64, col0 = bn * 32;
  const int r16 = lane & 15, q = lane >> 4;
  const int srow = lane >> 2;
  const int scol = (((lane & 3) ^ ((srow >> 1) & 3))) * 8;
  const int cqa = (q ^ ((r16 >> 1) & 3)) * 8;

  if (bn == 0 && tid < 64) {
    int b = row0 + tid;
    float c = 0.5f * (div0[b] + div1[b]);
    c = fminf(fmaxf(c, -100.f), 100.f);
    lp[b] -= wdt * c;
    div0[b] = 0.f; div1[b] = 0.f;
  }

  f32x4 acc[2];
  acc[0] = (f32x4){0,0,0,0}; acc[1] = (f32x4){0,0,0,0};

  const size_t arow = (size_t)(row0 + wave * 16 + srow) * 1024 + scol;
  const size_t brow = (size_t)(col0 + (wave & 1) * 16 + srow) * 1024 + scol;
  auto stage = [&](int kt, int buf) {
    u16* b = &S[buf][0];
    __builtin_amdgcn_global_load_lds((ga_u32*)(hbuf + arow + kt), (ls_u32*)(b + wave * 512), 16, 0, 0);
    if (wave < 2)
      __builtin_amdgcn_global_load_lds((ga_u32*)(W2T + brow + kt), (ls_u32*)(b + 4096 + wave * 512), 16, 0, 0);
  };
  stage(0, 0);
  for (int it = 0; it < 32; ++it) {
    const int buf = it & 1;
    __syncthreads();
    if (it + 1 < 32) stage((it + 1) * 32, buf ^ 1);
    const u16* b = &S[buf][0];
    s16x8 af  = *(const s16x8*)(b + (wave * 16 + r16) * 32 + cqa);
    s16x8 bf0 = *(const s16x8*)(b + 4096 + r16 * 32 + cqa);
    s16x8 bf1 = *(const s16x8*)(b + 4096 + (16 + r16) * 32 + cqa);
    acc[0] = __builtin_amdgcn_mfma_f32_16x16x32_bf16(af, bf0, acc[0], 0, 0, 0);
    acc[1] = __builtin_amdgcn_mfma_f32_16x16x32_bf16(af, bf1, acc[1], 0, 0, 0);
  }

#pragma unroll
  for (int j = 0; j < 2; ++j) {
    const int gcol = col0 + j * 16 + r16;
    const float cb = b2v[gcol];
    const int rbase = row0 + wave * 16 + q * 4;
#pragma unroll
    for (int r = 0; r < 4; ++r) {
      const size_t idx2 = (size_t)(rbase + r) * D_N + gcol;
      const float f = acc[j][r] + cb;
      if (ST == 0) {
        ACC[idx2] = dt * 0.125f * f;
        T[idx2]   = dt * f;
        zin[idx2] = f2bf(z[idx2] + dt * f * (1.f / 3.f));
      } else if (ST == 1) {
        float t_ = T[idx2];
        ACC[idx2] += 0.375f * dt * f;
        zin[idx2] = f2bf(z[idx2] + dt * f - t_ * (1.f / 3.f));
        T[idx2]   = t_ - dt * f;
      } else if (ST == 2) {
        ACC[idx2] += 0.375f * dt * f;
        zin[idx2] = f2bf(z[idx2] + T[idx2] + dt * f);
      } else {
        float zn = z[idx2] + ACC[idx2] + dt * 0.125f * f;
        z[idx2]   = zn;
        zin[idx2] = f2bf(zn);
      }
    }
  }
}

// out = [rep (f32, BxD) ; logprob (f32, B)] — XCD-affine row mapping.
__global__ void k_out(const float* __restrict__ z, const float* __restrict__ lp,
                      float* __restrict__ out) {
  const int xcd = blockIdx.x & 7, idx = blockIdx.x >> 3;    // 2048 blocks
  const int b = (xcd * 4 + (idx >> 6)) * 64 + (idx & 63);
  int t = threadIdx.x;
  const float* zr = z + (size_t)b * D_N;
  float ss = 0.f;
  for (int d = t; d < D_N; d += 256) {
    float v = zr[d];
    out[(size_t)b * D_N + d] = v;
    ss += v * v;
  }
  for (int off = 32; off > 0; off >>= 1) ss += __shfl_down(ss, off);
  __shared__ float red[4];
  if ((t & 63) == 0) red[t >> 6] = ss;
  __syncthreads();
  if (t == 0) out[(size_t)BD + b] = -0.5f * (red[0] + red[1] + red[2] + red[3]) + lp[b];
}

extern "C" void kernel_launch(void* const* d_in, const int* in_sizes, int n_in,
                              void* d_out, int out_size, void* d_ws, size_t ws_size,
                              hipStream_t stream) {
  const float* x   = (const float*)d_in[0];
  const float* W1  = (const float*)d_in[1];
  const float* b1  = (const float*)d_in[2];
  const float* tw1 = (const float*)d_in[3];
  const float* W2  = (const float*)d_in[4];
  const float* b2  = (const float*)d_in[5];
  float* outp = (float*)d_out;

  const size_t NEEDED = (size_t)45 << 20;
  if (ws_size < NEEDED) {
    k_sentinel<<<(BD + B_N + 255) / 256, 256, 0, stream>>>(outp, BD + B_N);
    return;
  }
  char* w = (char*)d_ws;
  auto carve = [&](size_t bytes) { char* p = w; w += (bytes + 255) & ~(size_t)255; return p; };
  uint32_t* keys = (uint32_t*)carve(144 * sizeof(uint32_t));
  u16* ebf   = (u16*)carve((size_t)4 * 2 * BD * 2);               // 16 MB: 4-slot e ring
  float* z   = (float*)carve((size_t)BD * 4);
  float* ACC = (float*)carve((size_t)BD * 4);
  float* T   = (float*)carve((size_t)BD * 4);
  u16* zin   = (u16*)carve((size_t)BD * 2);
  u16* hbuf  = (u16*)carve((size_t)B_N * H_N * 2);
  u16* W1T   = (u16*)carve((size_t)H_N * D_N * 2);
  u16* W2b   = (u16*)carve((size_t)H_N * D_N * 2);
  u16* W2T   = (u16*)carve((size_t)D_N * H_N * 2);
  float* lp   = (float*)carve((size_t)B_N * 4);
  float* div0 = (float*)carve((size_t)B_N * 4);
  float* div1 = (float*)carve((size_t)B_N * 4);

  k_keysched<<<1, 1, 0, stream>>>(keys);
  k_init<<<BD / 256, 256, 0, stream>>>(x, z, zin, lp, div0, div1);
  k_cvtT<<<(D_N * H_N) / 256, 256, 0, stream>>>(W1, W1T, D_N, H_N);
  k_cvt <<<(H_N * D_N) / 256, 256, 0, stream>>>(W2, W2b, H_N * D_N);
  k_cvtT<<<(H_N * D_N) / 256, 256, 0, stream>>>(W2, W2T, H_N, D_N);

  const int gF1 = (B_N / 64) * (H_N / 64);   // 512
  const int gF3 = (B_N / 64) * (D_N / 32);   // 512

  for (int s = 0; s < 9; ++s) {
    float t0 = (float)s / 9.0f;
    float t1 = (float)(s + 1) / 9.0f;
    float dt = t1 - t0;
    float tst[4] = { t0, t0 + dt / 3.0f, t0 + dt * 2.0f / 3.0f, t1 };
    float wts[4] = { 1.f, 3.f, 3.f, 1.f };
    for (int st = 0; st < 4; ++st) {
      const int sg = s * 4 + st;
      if ((sg & 3) == 0) k_egen<<<1024, 256, 0, stream>>>(ebf, keys, sg);
      const u16* e0g = ebf + (size_t)(sg & 3) * (2 * (size_t)BD);
      const u16* e1g = e0g + BD;
      k_f1<<<gF1, 256, 0, stream>>>(zin, e0g, e1g, W1T, W2b, b1, tw1, tst[st], hbuf, div0, div1);
      const float wdt = dt * 0.125f * wts[st];
      if (st == 0)      k_f3<0><<<gF3, 256, 0, stream>>>(hbuf, W2T, b2, z, ACC, T, zin, dt, lp, div0, div1, wdt);
      else if (st == 1) k_f3<1><<<gF3, 256, 0, stream>>>(hbuf, W2T, b2, z, ACC, T, zin, dt, lp, div0, div1, wdt);
      else if (st == 2) k_f3<2><<<gF3, 256, 0, stream>>>(hbuf, W2T, b2, z, ACC, T, zin, dt, lp, div0, div1, wdt);
      else              k_f3<3><<<gF3, 256, 0, stream>>>(hbuf, W2T, b2, z, ACC, T, zin, dt, lp, div0, div1, wdt);
    }
  }
  k_out<<<B_N, 256, 0, stream>>>(z, lp, outp);
}